// Round 11
// baseline (157.381 us; speedup 1.0000x reference)
//
#include <hip/hip_runtime.h>

#define DIM 64
#define NBUCK 256
#define BSHIFT 9
#define BCAP 12288
#define CHUNK 1024

typedef __attribute__((ext_vector_type(4))) float f32x4;
typedef __attribute__((ext_vector_type(2))) float f32x2v;
typedef __attribute__((ext_vector_type(8))) short short8;

#define MFMA16(a, b, c) __builtin_amdgcn_mfma_f32_16x16x32_bf16(a, b, c, 0, 0, 0)

template <int CTRL>
__device__ __forceinline__ float qperm(float v) {
    return __int_as_float(__builtin_amdgcn_update_dpp(
        0, __float_as_int(v), CTRL, 0xF, 0xF, true));
}

// split fp32 -> bf16 hi + bf16 lo (truncation; dropped term ~2^-16 rel)
__device__ __forceinline__ void cvt8(const float* f, short8& hi, short8& lo) {
#pragma unroll
    for (int e = 0; e < 8; ++e) {
        const unsigned u = __float_as_uint(f[e]);
        hi[e] = (short)(u >> 16);
        const float hf = __uint_as_float(u & 0xFFFF0000u);
        lo[e] = (short)(__float_as_uint(f[e] - hf) >> 16);
    }
}

__device__ __forceinline__ unsigned short bf16rne(float f) {
    const unsigned u = __float_as_uint(f);
    return (unsigned short)((u + 0x7FFFu + ((u >> 16) & 1u)) >> 16);
}

// Pre-convert the 4 weight matrices into MFMA B-fragment order; zero bcursor.
__global__ __launch_bounds__(256) void prep_kernel(
    const float* __restrict__ Wl, const float* __restrict__ Wh,
    const float* __restrict__ W1, const float* __restrict__ W2,
    short8* __restrict__ wf, int* __restrict__ bcursor)
{
    const int tid = threadIdx.x;
    bcursor[tid] = 0;
    const int m = tid >> 6, l = tid & 63;
    const float* W = (m == 0) ? Wl : (m == 1) ? Wh : (m == 2) ? W1 : W2;
    const int o = l & 15;
    const int kg = (l >> 4) * 8;
#pragma unroll
    for (int t = 0; t < 4; ++t)
#pragma unroll
        for (int s = 0; s < 2; ++s) {
            float f[8];
#pragma unroll
            for (int e = 0; e < 8; ++e)
                f[e] = W[(o + 16 * t) * DIM + 32 * s + kg + e];
            short8 hi, lo;
            cvt8(f, hi, lo);
            const int base = (((m * 4 + t) * 2 + s) * 2);
            wf[(base + 0) * 64 + l] = hi;
            wf[(base + 1) * 64 + l] = lo;
        }
}

// h = x @ Wl^T + b via split-bf16 MFMA; also emits bf16 mirror hb for gathers.
__global__ __launch_bounds__(256, 3) void gemm64_kernel(
    const float* __restrict__ x, const short8* __restrict__ wf,
    const float* __restrict__ bias, float* __restrict__ h,
    unsigned short* __restrict__ hb, int N)
{
    const int l = threadIdx.x & 63;
    const int gw = blockIdx.x * 4 + (threadIdx.x >> 6);
    const int nw = gridDim.x * 4;
    const int nstrips = (N + 15) >> 4;
    const int lr = l & 15, lk = (l >> 4) * 8, lrow4 = (l >> 4) * 4;

    short8 wh_[4][2], wl_[4][2];
#pragma unroll
    for (int t = 0; t < 4; ++t)
#pragma unroll
        for (int s = 0; s < 2; ++s) {
            wh_[t][s] = wf[(((0 * 4 + t) * 2 + s) * 2 + 0) * 64 + l];
            wl_[t][s] = wf[(((0 * 4 + t) * 2 + s) * 2 + 1) * 64 + l];
        }
    float b4[4];
#pragma unroll
    for (int t = 0; t < 4; ++t) b4[t] = bias[lr + 16 * t];

    for (int strip = gw; strip < nstrips; strip += nw) {
        const int rbase = strip * 16;
        const int arow = min(rbase + lr, N - 1);
        short8 ah[2], al[2];
#pragma unroll
        for (int s = 0; s < 2; ++s) {
            const float4 p0 = *reinterpret_cast<const float4*>(x + (size_t)arow * DIM + 32 * s + lk);
            const float4 p1 = *reinterpret_cast<const float4*>(x + (size_t)arow * DIM + 32 * s + lk + 4);
            float f[8] = {p0.x, p0.y, p0.z, p0.w, p1.x, p1.y, p1.z, p1.w};
            cvt8(f, ah[s], al[s]);
        }
        f32x4 acc[4];
#pragma unroll
        for (int t = 0; t < 4; ++t) acc[t] = (f32x4){b4[t], b4[t], b4[t], b4[t]};
#pragma unroll
        for (int s = 0; s < 2; ++s) {
#pragma unroll
            for (int t = 0; t < 4; ++t) acc[t] = MFMA16(ah[s], wh_[t][s], acc[t]);
#pragma unroll
            for (int t = 0; t < 4; ++t) acc[t] = MFMA16(ah[s], wl_[t][s], acc[t]);
#pragma unroll
            for (int t = 0; t < 4; ++t) acc[t] = MFMA16(al[s], wh_[t][s], acc[t]);
        }
#pragma unroll
        for (int t = 0; t < 4; ++t)
#pragma unroll
            for (int rg = 0; rg < 4; ++rg) {
                const int row = rbase + lrow4 + rg;
                if (row < N) {
                    h[(size_t)row * DIM + lr + 16 * t] = acc[t][rg];
                    hb[(size_t)row * DIM + lr + 16 * t] = bf16rne(acc[t][rg]);
                }
            }
    }
}

// fused tail via split-bf16 MFMA
__global__ __launch_bounds__(256, 2) void tail_kernel(
    const float* __restrict__ aggr, const float* __restrict__ hres,
    const short8* __restrict__ wf,
    const float* __restrict__ bh, const float* __restrict__ b1,
    const float* __restrict__ b2, const float* __restrict__ eps,
    float* __restrict__ out, int N)
{
    __shared__ float zb[4][16 * 68];
    const int l = threadIdx.x & 63;
    const int w = threadIdx.x >> 6;
    const int gw = blockIdx.x * 4 + w;
    const int nw = gridDim.x * 4;
    const int nstrips = (N + 15) >> 4;
    const int lr = l & 15, lk = (l >> 4) * 8, lrow4 = (l >> 4) * 4;
    float* zw = zb[w];

    short8 whh[4][2], w1h[4][2], w2h[4][2];
#pragma unroll
    for (int t = 0; t < 4; ++t)
#pragma unroll
        for (int s = 0; s < 2; ++s) {
            whh[t][s] = wf[(((1 * 4 + t) * 2 + s) * 2 + 0) * 64 + l];
            w1h[t][s] = wf[(((2 * 4 + t) * 2 + s) * 2 + 0) * 64 + l];
            w2h[t][s] = wf[(((3 * 4 + t) * 2 + s) * 2 + 0) * 64 + l];
        }
    float bh4[4], b14[4], b24[4];
#pragma unroll
    for (int t = 0; t < 4; ++t) {
        bh4[t] = bh[lr + 16 * t];
        b14[t] = b1[lr + 16 * t];
        b24[t] = b2[lr + 16 * t];
    }
    const float escale = 1.0f + eps[0];

    for (int strip = gw; strip < nstrips; strip += nw) {
        const int rbase = strip * 16;

        float vh[4][4];
#pragma unroll
        for (int t = 0; t < 4; ++t)
#pragma unroll
            for (int rg = 0; rg < 4; ++rg)
                vh[t][rg] = hres[(size_t)min(rbase + lrow4 + rg, N - 1) * DIM + lr + 16 * t];

        // ---- stage 1: aggr @ Wh^T ----
        const int arow = min(rbase + lr, N - 1);
        short8 ah[2], al[2];
#pragma unroll
        for (int s = 0; s < 2; ++s) {
            const float4 p0 = *reinterpret_cast<const float4*>(aggr + (size_t)arow * DIM + 32 * s + lk);
            const float4 p1 = *reinterpret_cast<const float4*>(aggr + (size_t)arow * DIM + 32 * s + lk + 4);
            float f[8] = {p0.x, p0.y, p0.z, p0.w, p1.x, p1.y, p1.z, p1.w};
            cvt8(f, ah[s], al[s]);
        }
        short8 lo_[4][2];
#pragma unroll
        for (int t = 0; t < 4; ++t)
#pragma unroll
            for (int s = 0; s < 2; ++s)
                lo_[t][s] = wf[(((1 * 4 + t) * 2 + s) * 2 + 1) * 64 + l];
        f32x4 acc[4];
#pragma unroll
        for (int t = 0; t < 4; ++t) acc[t] = (f32x4){bh4[t], bh4[t], bh4[t], bh4[t]};
#pragma unroll
        for (int s = 0; s < 2; ++s) {
#pragma unroll
            for (int t = 0; t < 4; ++t) acc[t] = MFMA16(ah[s], whh[t][s], acc[t]);
#pragma unroll
            for (int t = 0; t < 4; ++t) acc[t] = MFMA16(ah[s], lo_[t][s], acc[t]);
#pragma unroll
            for (int t = 0; t < 4; ++t) acc[t] = MFMA16(al[s], whh[t][s], acc[t]);
        }
#pragma unroll
        for (int t = 0; t < 4; ++t)
#pragma unroll
            for (int rg = 0; rg < 4; ++rg)
                zw[(lrow4 + rg) * 68 + lr + 16 * t] = fmaf(escale, vh[t][rg], acc[t][rg]);
        asm volatile("s_waitcnt lgkmcnt(0)" ::: "memory");

        // ---- stage 2: z @ W1^T, relu ----
        short8 zh[2], zl[2];
#pragma unroll
        for (int s = 0; s < 2; ++s) {
            const float4 q0 = *reinterpret_cast<const float4*>(zw + lr * 68 + 32 * s + lk);
            const float4 q1 = *reinterpret_cast<const float4*>(zw + lr * 68 + 32 * s + lk + 4);
            float f[8] = {q0.x, q0.y, q0.z, q0.w, q1.x, q1.y, q1.z, q1.w};
            cvt8(f, zh[s], zl[s]);
        }
#pragma unroll
        for (int t = 0; t < 4; ++t)
#pragma unroll
            for (int s = 0; s < 2; ++s)
                lo_[t][s] = wf[(((2 * 4 + t) * 2 + s) * 2 + 1) * 64 + l];
#pragma unroll
        for (int t = 0; t < 4; ++t) acc[t] = (f32x4){b14[t], b14[t], b14[t], b14[t]};
#pragma unroll
        for (int s = 0; s < 2; ++s) {
#pragma unroll
            for (int t = 0; t < 4; ++t) acc[t] = MFMA16(zh[s], w1h[t][s], acc[t]);
#pragma unroll
            for (int t = 0; t < 4; ++t) acc[t] = MFMA16(zh[s], lo_[t][s], acc[t]);
#pragma unroll
            for (int t = 0; t < 4; ++t) acc[t] = MFMA16(zl[s], w1h[t][s], acc[t]);
        }
#pragma unroll
        for (int t = 0; t < 4; ++t)
#pragma unroll
            for (int rg = 0; rg < 4; ++rg)
                zw[(lrow4 + rg) * 68 + lr + 16 * t] = fmaxf(acc[t][rg], 0.f);
        asm volatile("s_waitcnt lgkmcnt(0)" ::: "memory");

        // ---- stage 3: hid @ W2^T ----
        short8 hh[2], hl[2];
#pragma unroll
        for (int s = 0; s < 2; ++s) {
            const float4 q0 = *reinterpret_cast<const float4*>(zw + lr * 68 + 32 * s + lk);
            const float4 q1 = *reinterpret_cast<const float4*>(zw + lr * 68 + 32 * s + lk + 4);
            float f[8] = {q0.x, q0.y, q0.z, q0.w, q1.x, q1.y, q1.z, q1.w};
            cvt8(f, hh[s], hl[s]);
        }
#pragma unroll
        for (int t = 0; t < 4; ++t)
#pragma unroll
            for (int s = 0; s < 2; ++s)
                lo_[t][s] = wf[(((3 * 4 + t) * 2 + s) * 2 + 1) * 64 + l];
#pragma unroll
        for (int t = 0; t < 4; ++t) acc[t] = (f32x4){b24[t], b24[t], b24[t], b24[t]};
#pragma unroll
        for (int s = 0; s < 2; ++s) {
#pragma unroll
            for (int t = 0; t < 4; ++t) acc[t] = MFMA16(hh[s], w2h[t][s], acc[t]);
#pragma unroll
            for (int t = 0; t < 4; ++t) acc[t] = MFMA16(hh[s], lo_[t][s], acc[t]);
#pragma unroll
            for (int t = 0; t < 4; ++t) acc[t] = MFMA16(hl[s], w2h[t][s], acc[t]);
        }
#pragma unroll
        for (int t = 0; t < 4; ++t)
#pragma unroll
            for (int rg = 0; rg < 4; ++rg) {
                const int row = rbase + lrow4 + rg;
                if (row < N) out[(size_t)row * DIM + lr + 16 * t] = acc[t][rg];
            }
    }
}

__device__ __forceinline__ int wave_incl_scan(int v, int lane) {
#pragma unroll
    for (int off = 1; off < 64; off <<= 1) {
        int t = __shfl_up(v, (unsigned)off, 64);
        if (lane >= off) v += t;
    }
    return v;
}

// Bin edges into 256 buckets; 4 edges/thread, int4 loads.
__global__ __launch_bounds__(256) void bin_kernel(
    const int* __restrict__ ei, const int* __restrict__ sgn,
    int* __restrict__ bcursor, int* __restrict__ records, int E)
{
    const int tid = threadIdx.x;
    const int base = blockIdx.x * CHUNK;
    __shared__ int lcnt[NBUCK];
    __shared__ int lbase[NBUCK];
    lcnt[tid] = 0;
    __syncthreads();
    const int lim = min(CHUNK, E - base);
    if (lim == CHUNK && (E & 3) == 0) {
        int r[4];
        {
            const int4 a = *(reinterpret_cast<const int4*>(ei + base) + tid);
            r[0]=a.x; r[1]=a.y; r[2]=a.z; r[3]=a.w;
        }
#pragma unroll
        for (int i = 0; i < 4; ++i) atomicAdd(&lcnt[r[i] >> BSHIFT], 1);
        __syncthreads();
        const int c = lcnt[tid];
        lbase[tid] = c ? atomicAdd(&bcursor[tid], c) : 0;
        lcnt[tid] = 0;
        __syncthreads();
        int cc[4], ss[4];
        {
            const int4 a = *(reinterpret_cast<const int4*>(ei + E + base) + tid);
            cc[0]=a.x; cc[1]=a.y; cc[2]=a.z; cc[3]=a.w;
            const int4 s2 = *(reinterpret_cast<const int4*>(sgn + base) + tid);
            ss[0]=s2.x; ss[1]=s2.y; ss[2]=s2.z; ss[3]=s2.w;
        }
#pragma unroll
        for (int i = 0; i < 4; ++i) {
            const int bkt = r[i] >> BSHIFT;
            const int idx = lbase[bkt] + atomicAdd(&lcnt[bkt], 1);
            if (idx < BCAP)
                records[bkt * BCAP + idx] = cc[i] | (ss[i] << 17) | ((r[i] & 511) << 18);
        }
    } else {
        for (int k = tid; k < lim; k += 256)
            atomicAdd(&lcnt[ei[base + k] >> BSHIFT], 1);
        __syncthreads();
        const int c = lcnt[tid];
        lbase[tid] = c ? atomicAdd(&bcursor[tid], c) : 0;
        lcnt[tid] = 0;
        __syncthreads();
        for (int k = tid; k < lim; k += 256) {
            const int e = base + k;
            const int rr = ei[e];
            const int cc2 = ei[E + e];
            const int s = sgn[e];
            const int b = rr >> BSHIFT;
            const int idx = lbase[b] + atomicAdd(&lcnt[b], 1);
            if (idx < BCAP)
                records[b * BCAP + idx] = cc2 | (s << 17) | ((rr & 511) << 18);
        }
    }
}

// exclusive scan of bucket counts; also writes 512 sentinel records after E
__global__ __launch_bounds__(256) void scan256_kernel(
    const int* __restrict__ bcursor, int* __restrict__ csrb,
    int* __restrict__ offsets, int* __restrict__ edata, int N, int E)
{
    const int tid = threadIdx.x, lane = tid & 63, w = tid >> 6;
    const int v = min(bcursor[tid], BCAP);
    const int inc = wave_incl_scan(v, lane);
    __shared__ int wtot[4];
    if (lane == 63) wtot[w] = inc;
    __syncthreads();
    int add = 0;
#pragma unroll
    for (int i = 0; i < 4; ++i)
        if (i < w) add += wtot[i];
    csrb[tid] = add + inc - v;
    if (tid == 0) offsets[N] = E;
    edata[E + tid] = 0;
    edata[E + 256 + tid] = 0;
}

__global__ __launch_bounds__(256) void build_kernel(
    const int* __restrict__ records, const int* __restrict__ bcursor,
    const int* __restrict__ csrb, int* __restrict__ offsets,
    int* __restrict__ edata, int N)
{
    const int b = blockIdx.x;
    const int tid = threadIdx.x, lane = tid & 63, w = tid >> 6;
    const int nbase = b << BSHIFT;
    const int nn = min(512, N - nbase);
    if (nn <= 0) return;
    const int cnt = min(bcursor[b], BCAP);
    const int base_csr = csrb[b];
    const int* rec = records + b * BCAP;

    __shared__ int ncnt[512];
    __shared__ int wtot[8];
    __shared__ int stag[BCAP];

    ncnt[tid] = 0; ncnt[256 + tid] = 0;
    __syncthreads();
    for (int i = tid; i < cnt; i += 256)
        atomicAdd(&ncnt[rec[i] >> 18], 1);
    __syncthreads();
    const int v0 = ncnt[tid], v1 = ncnt[256 + tid];
    const int i0 = wave_incl_scan(v0, lane);
    if (lane == 63) wtot[w] = i0;
    const int i1 = wave_incl_scan(v1, lane);
    if (lane == 63) wtot[4 + w] = i1;
    __syncthreads();
    int a0 = 0, a1 = 0;
#pragma unroll
    for (int i = 0; i < 4; ++i) {
        if (i < w) { a0 += wtot[i]; a1 += wtot[4 + i]; }
    }
    const int half = wtot[0] + wtot[1] + wtot[2] + wtot[3];
    const int e0 = a0 + i0 - v0;
    const int e1 = half + a1 + i1 - v1;
    if (tid < nn)       offsets[nbase + tid]       = base_csr + e0;
    if (256 + tid < nn) offsets[nbase + 256 + tid] = base_csr + e1;
    __syncthreads();
    ncnt[tid] = e0; ncnt[256 + tid] = e1;
    __syncthreads();
    for (int i = tid; i < cnt; i += 256) {
        const int rcd = rec[i];
        const int p = atomicAdd(&ncnt[rcd >> 18], 1);
        stag[p] = (rcd & 0x1FFFF) | (((rcd >> 17) & 1) << 20);
    }
    __syncthreads();
    for (int i = tid; i < cnt; i += 256)
        edata[base_csr + i] = stag[i];
}

// 4 nodes/wave, 16 lanes/node, bf16 gathers; 32-bit saddr offsets; 8-deep
// unroll for MLP; out-of-segment slots gather hb row 0 (hot line) via cndmask.
__global__ __launch_bounds__(256) void attn_kernel(
    const float* __restrict__ h, const unsigned short* __restrict__ hb,
    const int* __restrict__ offsets, const int* __restrict__ edata,
    const float* __restrict__ sign_tab, float* __restrict__ aggr, int n)
{
    const int lane = threadIdx.x & 63;
    const int gl   = lane & 15;
    const int node = blockIdx.x * 16 + ((threadIdx.x >> 6) << 2) + (lane >> 4);
    const bool alive = node < n;
    const int nidx = alive ? node : 0;

    const int beg = offsets[nidx];
    const int deg = offsets[nidx + 1] - beg;

    const float4 hi = *reinterpret_cast<const float4*>(h + ((unsigned)nidx << 6) + (gl << 2));
    const float4 s0 = *reinterpret_cast<const float4*>(sign_tab + ((gl & 3) << 2));
    const float4 s1 = *reinterpret_cast<const float4*>(sign_tab + 16 + ((gl & 3) << 2));
    const f32x2v hs0a = {hi.x * s0.x, hi.y * s0.y};
    const f32x2v hs0b = {hi.z * s0.z, hi.w * s0.w};
    const f32x2v hs1a = {hi.x * s1.x, hi.y * s1.y};
    const f32x2v hs1b = {hi.z * s1.z, hi.w * s1.w};

    int maxdeg = max(deg, __shfl_xor(deg, 16, 64));
    maxdeg = max(maxdeg, __shfl_xor(maxdeg, 32, 64));

    float den = 0.f;
    f32x2v ma = {0.f, 0.f}, mb = {0.f, 0.f};
    const unsigned glb = (unsigned)(gl << 3);   // byte offset within a 128B row

    for (int e = 0; e < maxdeg; e += 8) {
        int pk[8];
#pragma unroll
        for (int u = 0; u < 8; ++u)
            pk[u] = edata[(unsigned)(beg + e + u)];
        uint2 v[8];
#pragma unroll
        for (int u = 0; u < 8; ++u) {
            unsigned off = (((unsigned)pk[u] & 0x1FFFFu) << 7) + glb;
            off = (e + u < deg) ? off : glb;   // junk slots hit row 0 (hot)
            v[u] = *reinterpret_cast<const uint2*>(
                reinterpret_cast<const char*>(hb) + off);
        }
#pragma unroll
        for (int u = 0; u < 8; ++u) {
            const f32x2v ha = {__uint_as_float(v[u].x << 16),
                               __uint_as_float(v[u].x & 0xFFFF0000u)};
            const f32x2v hc = {__uint_as_float(v[u].y << 16),
                               __uint_as_float(v[u].y & 0xFFFF0000u)};
            const bool sg = (pk[u] >> 20) & 1;
            const f32x2v wa = sg ? hs1a : hs0a;
            const f32x2v wb = sg ? hs1b : hs0b;
            const f32x2v p = wa * ha + wb * hc;
            float sc = p.x + p.y;
            sc += qperm<0xB1>(sc);
            sc += qperm<0x4E>(sc);
            const float ex = (e + u < deg) ? __expf(sc) : 0.f;
            den += ex;
            ma += ex * ha;
            mb += ex * hc;
        }
    }

    if (alive) {
        const float inv = 1.0f / (den + 1e-16f);
        float4 o = make_float4(ma.x * inv, ma.y * inv, mb.x * inv, mb.y * inv);
        *reinterpret_cast<float4*>(aggr + ((unsigned)node << 6) + (gl << 2)) = o;
    }
}

extern "C" void kernel_launch(void* const* d_in, const int* in_sizes, int n_in,
                              void* d_out, int out_size, void* d_ws, size_t ws_size,
                              hipStream_t stream) {
    const float* x        = (const float*)d_in[0];
    const int*   ei       = (const int*)d_in[1];
    const int*   esign    = (const int*)d_in[2];
    const float* Wl_w     = (const float*)d_in[3];
    const float* Wl_b     = (const float*)d_in[4];
    const float* sign_tab = (const float*)d_in[5];
    const float* Wh_w     = (const float*)d_in[6];
    const float* Wh_b     = (const float*)d_in[7];
    const float* w1       = (const float*)d_in[8];
    const float* b1       = (const float*)d_in[9];
    const float* w2       = (const float*)d_in[10];
    const float* b2       = (const float*)d_in[11];
    const float* eps      = (const float*)d_in[12];
    float* out = (float*)d_out;

    const int N = in_sizes[0] / DIM;
    const int E = in_sizes[2];

    float* h       = (float*)d_ws;
    float* aggr    = h + (size_t)N * DIM;
    int*   records = (int*)aggr;                 // alias: dead before attn writes aggr
    int*   edata   = (int*)(aggr + (size_t)N * DIM);
    int*   bcursor = edata + (E + 520);          // 512 sentinel slots + slack
    int*   csrb    = bcursor + NBUCK;
    int*   offsets = csrb + NBUCK;               // N+1 ints
    short8* wf     = (short8*)(offsets + ((N + 1 + 3) & ~3));  // 16KB, 16B-aligned
    unsigned short* hb = (unsigned short*)d_out; // bf16 mirror: d_out is dead
                                                 // scratch until tail overwrites it

    // weight fragment prep (hi/lo bf16, B-frag order) + bcursor zero
    prep_kernel<<<1, 256, 0, stream>>>(Wl_w, Wh_w, w1, w2, wf, bcursor);

    // h = x @ Wl^T + Wl_b  (MFMA) + bf16 mirror
    gemm64_kernel<<<512, 256, 0, stream>>>(x, wf, Wl_b, h, hb, N);

    // bucketed counting-sort CSR build
    bin_kernel<<<(E + CHUNK - 1) / CHUNK, 256, 0, stream>>>(ei, esign, bcursor, records, E);
    scan256_kernel<<<1, 256, 0, stream>>>(bcursor, csrb, offsets, edata, N, E);
    build_kernel<<<NBUCK, 256, 0, stream>>>(records, bcursor, csrb, offsets, edata, N);

    // segment softmax + aggregation (bf16 gathers)
    attn_kernel<<<(N + 15) / 16, 256, 0, stream>>>(h, hb, offsets, edata, sign_tab, aggr, N);

    // fused tail (MFMA): z -> relu mlp -> out
    tail_kernel<<<512, 256, 0, stream>>>(aggr, h, wf, Wh_b, b1, b2, eps, out, N);
}

// Round 12
// 136.121 us; speedup vs baseline: 1.1562x; 1.1562x over previous
//
#include <hip/hip_runtime.h>

#define DIM 64
#define NBUCK 256
#define BSHIFT 9
#define BCAP 12288
#define CHUNK 2048

typedef __attribute__((ext_vector_type(4))) float f32x4;
typedef __attribute__((ext_vector_type(2))) float f32x2v;
typedef __attribute__((ext_vector_type(8))) short short8;

#define MFMA16(a, b, c) __builtin_amdgcn_mfma_f32_16x16x32_bf16(a, b, c, 0, 0, 0)

template <int CTRL>
__device__ __forceinline__ float qperm(float v) {
    return __int_as_float(__builtin_amdgcn_update_dpp(
        0, __float_as_int(v), CTRL, 0xF, 0xF, true));
}

// split fp32 -> bf16 hi + bf16 lo (truncation; dropped term ~2^-16 rel)
__device__ __forceinline__ void cvt8(const float* f, short8& hi, short8& lo) {
#pragma unroll
    for (int e = 0; e < 8; ++e) {
        const unsigned u = __float_as_uint(f[e]);
        hi[e] = (short)(u >> 16);
        const float hf = __uint_as_float(u & 0xFFFF0000u);
        lo[e] = (short)(__float_as_uint(f[e] - hf) >> 16);
    }
}

__device__ __forceinline__ unsigned short bf16rne(float f) {
    const unsigned u = __float_as_uint(f);
    return (unsigned short)((u + 0x7FFFu + ((u >> 16) & 1u)) >> 16);
}

// Pre-convert the 4 weight matrices into MFMA B-fragment order; zero bcursor.
__global__ __launch_bounds__(256) void prep_kernel(
    const float* __restrict__ Wl, const float* __restrict__ Wh,
    const float* __restrict__ W1, const float* __restrict__ W2,
    short8* __restrict__ wf, int* __restrict__ bcursor)
{
    const int tid = threadIdx.x;
    bcursor[tid] = 0;
    const int m = tid >> 6, l = tid & 63;
    const float* W = (m == 0) ? Wl : (m == 1) ? Wh : (m == 2) ? W1 : W2;
    const int o = l & 15;
    const int kg = (l >> 4) * 8;
#pragma unroll
    for (int t = 0; t < 4; ++t)
#pragma unroll
        for (int s = 0; s < 2; ++s) {
            float f[8];
#pragma unroll
            for (int e = 0; e < 8; ++e)
                f[e] = W[(o + 16 * t) * DIM + 32 * s + kg + e];
            short8 hi, lo;
            cvt8(f, hi, lo);
            const int base = (((m * 4 + t) * 2 + s) * 2);
            wf[(base + 0) * 64 + l] = hi;
            wf[(base + 1) * 64 + l] = lo;
        }
}

// h = x @ Wl^T + b via split-bf16 MFMA; also emits bf16 mirror hb for gathers.
__global__ __launch_bounds__(256, 3) void gemm64_kernel(
    const float* __restrict__ x, const short8* __restrict__ wf,
    const float* __restrict__ bias, float* __restrict__ h,
    unsigned short* __restrict__ hb, int N)
{
    const int l = threadIdx.x & 63;
    const int gw = blockIdx.x * 4 + (threadIdx.x >> 6);
    const int nw = gridDim.x * 4;
    const int nstrips = (N + 15) >> 4;
    const int lr = l & 15, lk = (l >> 4) * 8, lrow4 = (l >> 4) * 4;

    short8 wh_[4][2], wl_[4][2];
#pragma unroll
    for (int t = 0; t < 4; ++t)
#pragma unroll
        for (int s = 0; s < 2; ++s) {
            wh_[t][s] = wf[(((0 * 4 + t) * 2 + s) * 2 + 0) * 64 + l];
            wl_[t][s] = wf[(((0 * 4 + t) * 2 + s) * 2 + 1) * 64 + l];
        }
    float b4[4];
#pragma unroll
    for (int t = 0; t < 4; ++t) b4[t] = bias[lr + 16 * t];

    for (int strip = gw; strip < nstrips; strip += nw) {
        const int rbase = strip * 16;
        const int arow = min(rbase + lr, N - 1);
        short8 ah[2], al[2];
#pragma unroll
        for (int s = 0; s < 2; ++s) {
            const float4 p0 = *reinterpret_cast<const float4*>(x + (size_t)arow * DIM + 32 * s + lk);
            const float4 p1 = *reinterpret_cast<const float4*>(x + (size_t)arow * DIM + 32 * s + lk + 4);
            float f[8] = {p0.x, p0.y, p0.z, p0.w, p1.x, p1.y, p1.z, p1.w};
            cvt8(f, ah[s], al[s]);
        }
        f32x4 acc[4];
#pragma unroll
        for (int t = 0; t < 4; ++t) acc[t] = (f32x4){b4[t], b4[t], b4[t], b4[t]};
#pragma unroll
        for (int s = 0; s < 2; ++s) {
#pragma unroll
            for (int t = 0; t < 4; ++t) acc[t] = MFMA16(ah[s], wh_[t][s], acc[t]);
#pragma unroll
            for (int t = 0; t < 4; ++t) acc[t] = MFMA16(ah[s], wl_[t][s], acc[t]);
#pragma unroll
            for (int t = 0; t < 4; ++t) acc[t] = MFMA16(al[s], wh_[t][s], acc[t]);
        }
#pragma unroll
        for (int t = 0; t < 4; ++t)
#pragma unroll
            for (int rg = 0; rg < 4; ++rg) {
                const int row = rbase + lrow4 + rg;
                if (row < N) {
                    h[(size_t)row * DIM + lr + 16 * t] = acc[t][rg];
                    hb[(size_t)row * DIM + lr + 16 * t] = bf16rne(acc[t][rg]);
                }
            }
    }
}

// fused tail via split-bf16 MFMA
__global__ __launch_bounds__(256, 2) void tail_kernel(
    const float* __restrict__ aggr, const float* __restrict__ hres,
    const short8* __restrict__ wf,
    const float* __restrict__ bh, const float* __restrict__ b1,
    const float* __restrict__ b2, const float* __restrict__ eps,
    float* __restrict__ out, int N)
{
    __shared__ float zb[4][16 * 68];
    const int l = threadIdx.x & 63;
    const int w = threadIdx.x >> 6;
    const int gw = blockIdx.x * 4 + w;
    const int nw = gridDim.x * 4;
    const int nstrips = (N + 15) >> 4;
    const int lr = l & 15, lk = (l >> 4) * 8, lrow4 = (l >> 4) * 4;
    float* zw = zb[w];

    short8 whh[4][2], w1h[4][2], w2h[4][2];
#pragma unroll
    for (int t = 0; t < 4; ++t)
#pragma unroll
        for (int s = 0; s < 2; ++s) {
            whh[t][s] = wf[(((1 * 4 + t) * 2 + s) * 2 + 0) * 64 + l];
            w1h[t][s] = wf[(((2 * 4 + t) * 2 + s) * 2 + 0) * 64 + l];
            w2h[t][s] = wf[(((3 * 4 + t) * 2 + s) * 2 + 0) * 64 + l];
        }
    float bh4[4], b14[4], b24[4];
#pragma unroll
    for (int t = 0; t < 4; ++t) {
        bh4[t] = bh[lr + 16 * t];
        b14[t] = b1[lr + 16 * t];
        b24[t] = b2[lr + 16 * t];
    }
    const float escale = 1.0f + eps[0];

    for (int strip = gw; strip < nstrips; strip += nw) {
        const int rbase = strip * 16;

        float vh[4][4];
#pragma unroll
        for (int t = 0; t < 4; ++t)
#pragma unroll
            for (int rg = 0; rg < 4; ++rg)
                vh[t][rg] = hres[(size_t)min(rbase + lrow4 + rg, N - 1) * DIM + lr + 16 * t];

        // ---- stage 1: aggr @ Wh^T ----
        const int arow = min(rbase + lr, N - 1);
        short8 ah[2], al[2];
#pragma unroll
        for (int s = 0; s < 2; ++s) {
            const float4 p0 = *reinterpret_cast<const float4*>(aggr + (size_t)arow * DIM + 32 * s + lk);
            const float4 p1 = *reinterpret_cast<const float4*>(aggr + (size_t)arow * DIM + 32 * s + lk + 4);
            float f[8] = {p0.x, p0.y, p0.z, p0.w, p1.x, p1.y, p1.z, p1.w};
            cvt8(f, ah[s], al[s]);
        }
        short8 lo_[4][2];
#pragma unroll
        for (int t = 0; t < 4; ++t)
#pragma unroll
            for (int s = 0; s < 2; ++s)
                lo_[t][s] = wf[(((1 * 4 + t) * 2 + s) * 2 + 1) * 64 + l];
        f32x4 acc[4];
#pragma unroll
        for (int t = 0; t < 4; ++t) acc[t] = (f32x4){bh4[t], bh4[t], bh4[t], bh4[t]};
#pragma unroll
        for (int s = 0; s < 2; ++s) {
#pragma unroll
            for (int t = 0; t < 4; ++t) acc[t] = MFMA16(ah[s], whh[t][s], acc[t]);
#pragma unroll
            for (int t = 0; t < 4; ++t) acc[t] = MFMA16(ah[s], lo_[t][s], acc[t]);
#pragma unroll
            for (int t = 0; t < 4; ++t) acc[t] = MFMA16(al[s], whh[t][s], acc[t]);
        }
#pragma unroll
        for (int t = 0; t < 4; ++t)
#pragma unroll
            for (int rg = 0; rg < 4; ++rg)
                zw[(lrow4 + rg) * 68 + lr + 16 * t] = fmaf(escale, vh[t][rg], acc[t][rg]);
        asm volatile("s_waitcnt lgkmcnt(0)" ::: "memory");

        // ---- stage 2: z @ W1^T, relu ----
        short8 zh[2], zl[2];
#pragma unroll
        for (int s = 0; s < 2; ++s) {
            const float4 q0 = *reinterpret_cast<const float4*>(zw + lr * 68 + 32 * s + lk);
            const float4 q1 = *reinterpret_cast<const float4*>(zw + lr * 68 + 32 * s + lk + 4);
            float f[8] = {q0.x, q0.y, q0.z, q0.w, q1.x, q1.y, q1.z, q1.w};
            cvt8(f, zh[s], zl[s]);
        }
#pragma unroll
        for (int t = 0; t < 4; ++t)
#pragma unroll
            for (int s = 0; s < 2; ++s)
                lo_[t][s] = wf[(((2 * 4 + t) * 2 + s) * 2 + 1) * 64 + l];
#pragma unroll
        for (int t = 0; t < 4; ++t) acc[t] = (f32x4){b14[t], b14[t], b14[t], b14[t]};
#pragma unroll
        for (int s = 0; s < 2; ++s) {
#pragma unroll
            for (int t = 0; t < 4; ++t) acc[t] = MFMA16(zh[s], w1h[t][s], acc[t]);
#pragma unroll
            for (int t = 0; t < 4; ++t) acc[t] = MFMA16(zh[s], lo_[t][s], acc[t]);
#pragma unroll
            for (int t = 0; t < 4; ++t) acc[t] = MFMA16(zl[s], w1h[t][s], acc[t]);
        }
#pragma unroll
        for (int t = 0; t < 4; ++t)
#pragma unroll
            for (int rg = 0; rg < 4; ++rg)
                zw[(lrow4 + rg) * 68 + lr + 16 * t] = fmaxf(acc[t][rg], 0.f);
        asm volatile("s_waitcnt lgkmcnt(0)" ::: "memory");

        // ---- stage 3: hid @ W2^T ----
        short8 hh[2], hl[2];
#pragma unroll
        for (int s = 0; s < 2; ++s) {
            const float4 q0 = *reinterpret_cast<const float4*>(zw + lr * 68 + 32 * s + lk);
            const float4 q1 = *reinterpret_cast<const float4*>(zw + lr * 68 + 32 * s + lk + 4);
            float f[8] = {q0.x, q0.y, q0.z, q0.w, q1.x, q1.y, q1.z, q1.w};
            cvt8(f, hh[s], hl[s]);
        }
#pragma unroll
        for (int t = 0; t < 4; ++t)
#pragma unroll
            for (int s = 0; s < 2; ++s)
                lo_[t][s] = wf[(((3 * 4 + t) * 2 + s) * 2 + 1) * 64 + l];
#pragma unroll
        for (int t = 0; t < 4; ++t) acc[t] = (f32x4){b24[t], b24[t], b24[t], b24[t]};
#pragma unroll
        for (int s = 0; s < 2; ++s) {
#pragma unroll
            for (int t = 0; t < 4; ++t) acc[t] = MFMA16(hh[s], w2h[t][s], acc[t]);
#pragma unroll
            for (int t = 0; t < 4; ++t) acc[t] = MFMA16(hh[s], lo_[t][s], acc[t]);
#pragma unroll
            for (int t = 0; t < 4; ++t) acc[t] = MFMA16(hl[s], w2h[t][s], acc[t]);
        }
#pragma unroll
        for (int t = 0; t < 4; ++t)
#pragma unroll
            for (int rg = 0; rg < 4; ++rg) {
                const int row = rbase + lrow4 + rg;
                if (row < N) out[(size_t)row * DIM + lr + 16 * t] = acc[t][rg];
            }
    }
}

__device__ __forceinline__ int wave_incl_scan(int v, int lane) {
#pragma unroll
    for (int off = 1; off < 64; off <<= 1) {
        int t = __shfl_up(v, (unsigned)off, 64);
        if (lane >= off) v += t;
    }
    return v;
}

// Bin edges into 256 buckets; 8 edges/thread, int4 loads (round-8/9 config:
// CHUNK 2048 measured fast; CHUNK 1024 regressed 3x via reserve-phase atomics).
__global__ __launch_bounds__(256) void bin_kernel(
    const int* __restrict__ ei, const int* __restrict__ sgn,
    int* __restrict__ bcursor, int* __restrict__ records, int E)
{
    const int tid = threadIdx.x;
    const int base = blockIdx.x * CHUNK;
    __shared__ int lcnt[NBUCK];
    __shared__ int lbase[NBUCK];
    lcnt[tid] = 0;
    __syncthreads();
    const int lim = min(CHUNK, E - base);
    if (lim == CHUNK && (E & 3) == 0) {
        int r[8];
        {
            const int4 a = *(reinterpret_cast<const int4*>(ei + base) + tid * 2);
            const int4 b = *(reinterpret_cast<const int4*>(ei + base) + tid * 2 + 1);
            r[0]=a.x; r[1]=a.y; r[2]=a.z; r[3]=a.w;
            r[4]=b.x; r[5]=b.y; r[6]=b.z; r[7]=b.w;
        }
#pragma unroll
        for (int i = 0; i < 8; ++i) atomicAdd(&lcnt[r[i] >> BSHIFT], 1);
        __syncthreads();
        const int c = lcnt[tid];
        lbase[tid] = c ? atomicAdd(&bcursor[tid], c) : 0;
        lcnt[tid] = 0;
        __syncthreads();
        int cc[8], ss[8];
        {
            const int4 a = *(reinterpret_cast<const int4*>(ei + E + base) + tid * 2);
            const int4 b = *(reinterpret_cast<const int4*>(ei + E + base) + tid * 2 + 1);
            cc[0]=a.x; cc[1]=a.y; cc[2]=a.z; cc[3]=a.w;
            cc[4]=b.x; cc[5]=b.y; cc[6]=b.z; cc[7]=b.w;
            const int4 s2 = *(reinterpret_cast<const int4*>(sgn + base) + tid * 2);
            const int4 s3 = *(reinterpret_cast<const int4*>(sgn + base) + tid * 2 + 1);
            ss[0]=s2.x; ss[1]=s2.y; ss[2]=s2.z; ss[3]=s2.w;
            ss[4]=s3.x; ss[5]=s3.y; ss[6]=s3.z; ss[7]=s3.w;
        }
#pragma unroll
        for (int i = 0; i < 8; ++i) {
            const int bkt = r[i] >> BSHIFT;
            const int idx = lbase[bkt] + atomicAdd(&lcnt[bkt], 1);
            if (idx < BCAP)
                records[bkt * BCAP + idx] = cc[i] | (ss[i] << 17) | ((r[i] & 511) << 18);
        }
    } else {
        for (int k = tid; k < lim; k += 256)
            atomicAdd(&lcnt[ei[base + k] >> BSHIFT], 1);
        __syncthreads();
        const int c = lcnt[tid];
        lbase[tid] = c ? atomicAdd(&bcursor[tid], c) : 0;
        lcnt[tid] = 0;
        __syncthreads();
        for (int k = tid; k < lim; k += 256) {
            const int e = base + k;
            const int rr = ei[e];
            const int cc2 = ei[E + e];
            const int s = sgn[e];
            const int b = rr >> BSHIFT;
            const int idx = lbase[b] + atomicAdd(&lcnt[b], 1);
            if (idx < BCAP)
                records[b * BCAP + idx] = cc2 | (s << 17) | ((rr & 511) << 18);
        }
    }
}

// exclusive scan of bucket counts; also writes 512 sentinel records after E
__global__ __launch_bounds__(256) void scan256_kernel(
    const int* __restrict__ bcursor, int* __restrict__ csrb,
    int* __restrict__ offsets, int* __restrict__ edata, int N, int E)
{
    const int tid = threadIdx.x, lane = tid & 63, w = tid >> 6;
    const int v = min(bcursor[tid], BCAP);
    const int inc = wave_incl_scan(v, lane);
    __shared__ int wtot[4];
    if (lane == 63) wtot[w] = inc;
    __syncthreads();
    int add = 0;
#pragma unroll
    for (int i = 0; i < 4; ++i)
        if (i < w) add += wtot[i];
    csrb[tid] = add + inc - v;
    if (tid == 0) offsets[N] = E;
    edata[E + tid] = 0;
    edata[E + 256 + tid] = 0;
}

__global__ __launch_bounds__(256) void build_kernel(
    const int* __restrict__ records, const int* __restrict__ bcursor,
    const int* __restrict__ csrb, int* __restrict__ offsets,
    int* __restrict__ edata, int N)
{
    const int b = blockIdx.x;
    const int tid = threadIdx.x, lane = tid & 63, w = tid >> 6;
    const int nbase = b << BSHIFT;
    const int nn = min(512, N - nbase);
    if (nn <= 0) return;
    const int cnt = min(bcursor[b], BCAP);
    const int base_csr = csrb[b];
    const int* rec = records + b * BCAP;

    __shared__ int ncnt[512];
    __shared__ int wtot[8];
    __shared__ int stag[BCAP];

    ncnt[tid] = 0; ncnt[256 + tid] = 0;
    __syncthreads();
    for (int i = tid; i < cnt; i += 256)
        atomicAdd(&ncnt[rec[i] >> 18], 1);
    __syncthreads();
    const int v0 = ncnt[tid], v1 = ncnt[256 + tid];
    const int i0 = wave_incl_scan(v0, lane);
    if (lane == 63) wtot[w] = i0;
    const int i1 = wave_incl_scan(v1, lane);
    if (lane == 63) wtot[4 + w] = i1;
    __syncthreads();
    int a0 = 0, a1 = 0;
#pragma unroll
    for (int i = 0; i < 4; ++i) {
        if (i < w) { a0 += wtot[i]; a1 += wtot[4 + i]; }
    }
    const int half = wtot[0] + wtot[1] + wtot[2] + wtot[3];
    const int e0 = a0 + i0 - v0;
    const int e1 = half + a1 + i1 - v1;
    if (tid < nn)       offsets[nbase + tid]       = base_csr + e0;
    if (256 + tid < nn) offsets[nbase + 256 + tid] = base_csr + e1;
    __syncthreads();
    ncnt[tid] = e0; ncnt[256 + tid] = e1;
    __syncthreads();
    for (int i = tid; i < cnt; i += 256) {
        const int rcd = rec[i];
        const int p = atomicAdd(&ncnt[rcd >> 18], 1);
        stag[p] = (rcd & 0x1FFFF) | (((rcd >> 17) & 1) << 20);
    }
    __syncthreads();
    for (int i = tid; i < cnt; i += 256)
        edata[base_csr + i] = stag[i];
}

// 4 nodes/wave, 16 lanes/node, bf16 gathers; 32-bit saddr offsets; 8-deep
// unroll; out-of-segment slots gather hb row 0 (hot line) via cndmask.
__global__ __launch_bounds__(256) void attn_kernel(
    const float* __restrict__ h, const unsigned short* __restrict__ hb,
    const int* __restrict__ offsets, const int* __restrict__ edata,
    const float* __restrict__ sign_tab, float* __restrict__ aggr, int n)
{
    const int lane = threadIdx.x & 63;
    const int gl   = lane & 15;
    const int node = blockIdx.x * 16 + ((threadIdx.x >> 6) << 2) + (lane >> 4);
    const bool alive = node < n;
    const int nidx = alive ? node : 0;

    const int beg = offsets[nidx];
    const int deg = offsets[nidx + 1] - beg;

    const float4 hi = *reinterpret_cast<const float4*>(h + ((unsigned)nidx << 6) + (gl << 2));
    const float4 s0 = *reinterpret_cast<const float4*>(sign_tab + ((gl & 3) << 2));
    const float4 s1 = *reinterpret_cast<const float4*>(sign_tab + 16 + ((gl & 3) << 2));
    const f32x2v hs0a = {hi.x * s0.x, hi.y * s0.y};
    const f32x2v hs0b = {hi.z * s0.z, hi.w * s0.w};
    const f32x2v hs1a = {hi.x * s1.x, hi.y * s1.y};
    const f32x2v hs1b = {hi.z * s1.z, hi.w * s1.w};

    int maxdeg = max(deg, __shfl_xor(deg, 16, 64));
    maxdeg = max(maxdeg, __shfl_xor(maxdeg, 32, 64));

    float den = 0.f;
    f32x2v ma = {0.f, 0.f}, mb = {0.f, 0.f};
    const unsigned glb = (unsigned)(gl << 3);   // byte offset within a 128B row

    for (int e = 0; e < maxdeg; e += 8) {
        int pk[8];
#pragma unroll
        for (int u = 0; u < 8; ++u)
            pk[u] = edata[(unsigned)(beg + e + u)];
        uint2 v[8];
#pragma unroll
        for (int u = 0; u < 8; ++u) {
            unsigned off = (((unsigned)pk[u] & 0x1FFFFu) << 7) + glb;
            off = (e + u < deg) ? off : glb;   // junk slots hit row 0 (hot)
            v[u] = *reinterpret_cast<const uint2*>(
                reinterpret_cast<const char*>(hb) + off);
        }
#pragma unroll
        for (int u = 0; u < 8; ++u) {
            const f32x2v ha = {__uint_as_float(v[u].x << 16),
                               __uint_as_float(v[u].x & 0xFFFF0000u)};
            const f32x2v hc = {__uint_as_float(v[u].y << 16),
                               __uint_as_float(v[u].y & 0xFFFF0000u)};
            const bool sg = (pk[u] >> 20) & 1;
            const f32x2v wa = sg ? hs1a : hs0a;
            const f32x2v wb = sg ? hs1b : hs0b;
            const f32x2v p = wa * ha + wb * hc;
            float sc = p.x + p.y;
            sc += qperm<0xB1>(sc);
            sc += qperm<0x4E>(sc);
            const float ex = (e + u < deg) ? __expf(sc) : 0.f;
            den += ex;
            ma += ex * ha;
            mb += ex * hc;
        }
    }

    if (alive) {
        const float inv = 1.0f / (den + 1e-16f);
        float4 o = make_float4(ma.x * inv, ma.y * inv, mb.x * inv, mb.y * inv);
        *reinterpret_cast<float4*>(aggr + ((unsigned)node << 6) + (gl << 2)) = o;
    }
}

extern "C" void kernel_launch(void* const* d_in, const int* in_sizes, int n_in,
                              void* d_out, int out_size, void* d_ws, size_t ws_size,
                              hipStream_t stream) {
    const float* x        = (const float*)d_in[0];
    const int*   ei       = (const int*)d_in[1];
    const int*   esign    = (const int*)d_in[2];
    const float* Wl_w     = (const float*)d_in[3];
    const float* Wl_b     = (const float*)d_in[4];
    const float* sign_tab = (const float*)d_in[5];
    const float* Wh_w     = (const float*)d_in[6];
    const float* Wh_b     = (const float*)d_in[7];
    const float* w1       = (const float*)d_in[8];
    const float* b1       = (const float*)d_in[9];
    const float* w2       = (const float*)d_in[10];
    const float* b2       = (const float*)d_in[11];
    const float* eps      = (const float*)d_in[12];
    float* out = (float*)d_out;

    const int N = in_sizes[0] / DIM;
    const int E = in_sizes[2];

    float* h       = (float*)d_ws;
    float* aggr    = h + (size_t)N * DIM;
    int*   records = (int*)aggr;                 // alias: dead before attn writes aggr
    int*   edata   = (int*)(aggr + (size_t)N * DIM);
    int*   bcursor = edata + (E + 520);          // 512 sentinel slots + slack
    int*   csrb    = bcursor + NBUCK;
    int*   offsets = csrb + NBUCK;               // N+1 ints
    short8* wf     = (short8*)(offsets + ((N + 1 + 3) & ~3));  // 16KB, 16B-aligned
    unsigned short* hb = (unsigned short*)d_out; // bf16 mirror: d_out is dead
                                                 // scratch until tail overwrites it

    // weight fragment prep (hi/lo bf16, B-frag order) + bcursor zero
    prep_kernel<<<1, 256, 0, stream>>>(Wl_w, Wh_w, w1, w2, wf, bcursor);

    // h = x @ Wl^T + Wl_b  (MFMA) + bf16 mirror
    gemm64_kernel<<<512, 256, 0, stream>>>(x, wf, Wl_b, h, hb, N);

    // bucketed counting-sort CSR build
    bin_kernel<<<(E + CHUNK - 1) / CHUNK, 256, 0, stream>>>(ei, esign, bcursor, records, E);
    scan256_kernel<<<1, 256, 0, stream>>>(bcursor, csrb, offsets, edata, N, E);
    build_kernel<<<NBUCK, 256, 0, stream>>>(records, bcursor, csrb, offsets, edata, N);

    // segment softmax + aggregation (bf16 gathers)
    attn_kernel<<<(N + 15) / 16, 256, 0, stream>>>(h, hb, offsets, edata, sign_tab, aggr, N);

    // fused tail (MFMA): z -> relu mlp -> out
    tail_kernel<<<512, 256, 0, stream>>>(aggr, h, wf, Wh_b, b1, b2, eps, out, N);
}

// Round 13
// 124.655 us; speedup vs baseline: 1.2625x; 1.0920x over previous
//
#include <hip/hip_runtime.h>

#define DIM 64
#define NBUCK 256
#define BSHIFT 9
#define BCAP 12288
#define CHUNK 2048

typedef __attribute__((ext_vector_type(4))) float f32x4;
typedef __attribute__((ext_vector_type(2))) float f32x2v;
typedef __attribute__((ext_vector_type(8))) short short8;

#define MFMA16(a, b, c) __builtin_amdgcn_mfma_f32_16x16x32_bf16(a, b, c, 0, 0, 0)

template <int CTRL>
__device__ __forceinline__ float qperm(float v) {
    return __int_as_float(__builtin_amdgcn_update_dpp(
        0, __float_as_int(v), CTRL, 0xF, 0xF, true));
}

// split fp32 -> bf16 hi + bf16 lo (truncation; dropped term ~2^-16 rel)
__device__ __forceinline__ void cvt8(const float* f, short8& hi, short8& lo) {
#pragma unroll
    for (int e = 0; e < 8; ++e) {
        const unsigned u = __float_as_uint(f[e]);
        hi[e] = (short)(u >> 16);
        const float hf = __uint_as_float(u & 0xFFFF0000u);
        lo[e] = (short)(__float_as_uint(f[e] - hf) >> 16);
    }
}

__device__ __forceinline__ unsigned short bf16rne(float f) {
    const unsigned u = __float_as_uint(f);
    return (unsigned short)((u + 0x7FFFu + ((u >> 16) & 1u)) >> 16);
}

// Weight fragments (hi/lo bf16, B-frag order); zero bcursor; edata sentinels;
// offsets[N]=E.
__global__ __launch_bounds__(256) void prep_kernel(
    const float* __restrict__ Wl, const float* __restrict__ Wh,
    const float* __restrict__ W1, const float* __restrict__ W2,
    short8* __restrict__ wf, int* __restrict__ bcursor,
    int* __restrict__ edata, int* __restrict__ offsets, int N, int E)
{
    const int tid = threadIdx.x;
    bcursor[tid] = 0;
    edata[E + tid] = 0;
    edata[E + 256 + tid] = 0;
    if (tid == 0) offsets[N] = E;
    const int m = tid >> 6, l = tid & 63;
    const float* W = (m == 0) ? Wl : (m == 1) ? Wh : (m == 2) ? W1 : W2;
    const int o = l & 15;
    const int kg = (l >> 4) * 8;
#pragma unroll
    for (int t = 0; t < 4; ++t)
#pragma unroll
        for (int s = 0; s < 2; ++s) {
            float f[8];
#pragma unroll
            for (int e = 0; e < 8; ++e)
                f[e] = W[(o + 16 * t) * DIM + 32 * s + kg + e];
            short8 hi, lo;
            cvt8(f, hi, lo);
            const int base = (((m * 4 + t) * 2 + s) * 2);
            wf[(base + 0) * 64 + l] = hi;
            wf[(base + 1) * 64 + l] = lo;
        }
}

// Fused: odd blocks = h-projection GEMM (MFMA); even blocks = edge binning.
// Independent outputs; interleaving hides bin's atomic latency under gemm.
__global__ __launch_bounds__(256, 3) void gemmbin_kernel(
    const float* __restrict__ x, const short8* __restrict__ wf,
    const float* __restrict__ bias, float* __restrict__ h,
    unsigned short* __restrict__ hb, int N,
    const int* __restrict__ ei, const int* __restrict__ sgn,
    int* __restrict__ bcursor, int* __restrict__ records, int E, int NB)
{
    if (blockIdx.x & 1) {
        // ---------------- GEMM path ----------------
        const int l = threadIdx.x & 63;
        const int gw = (blockIdx.x >> 1) * 4 + (threadIdx.x >> 6);
        const int nw = NB * 4;
        const int nstrips = (N + 15) >> 4;
        const int lr = l & 15, lk = (l >> 4) * 8, lrow4 = (l >> 4) * 4;

        short8 wh_[4][2], wl_[4][2];
#pragma unroll
        for (int t = 0; t < 4; ++t)
#pragma unroll
            for (int s = 0; s < 2; ++s) {
                wh_[t][s] = wf[(((0 * 4 + t) * 2 + s) * 2 + 0) * 64 + l];
                wl_[t][s] = wf[(((0 * 4 + t) * 2 + s) * 2 + 1) * 64 + l];
            }
        float b4[4];
#pragma unroll
        for (int t = 0; t < 4; ++t) b4[t] = bias[lr + 16 * t];

        for (int strip = gw; strip < nstrips; strip += nw) {
            const int rbase = strip * 16;
            const int arow = min(rbase + lr, N - 1);
            short8 ah[2], al[2];
#pragma unroll
            for (int s = 0; s < 2; ++s) {
                const float4 p0 = *reinterpret_cast<const float4*>(x + (size_t)arow * DIM + 32 * s + lk);
                const float4 p1 = *reinterpret_cast<const float4*>(x + (size_t)arow * DIM + 32 * s + lk + 4);
                float f[8] = {p0.x, p0.y, p0.z, p0.w, p1.x, p1.y, p1.z, p1.w};
                cvt8(f, ah[s], al[s]);
            }
            f32x4 acc[4];
#pragma unroll
            for (int t = 0; t < 4; ++t) acc[t] = (f32x4){b4[t], b4[t], b4[t], b4[t]};
#pragma unroll
            for (int s = 0; s < 2; ++s) {
#pragma unroll
                for (int t = 0; t < 4; ++t) acc[t] = MFMA16(ah[s], wh_[t][s], acc[t]);
#pragma unroll
                for (int t = 0; t < 4; ++t) acc[t] = MFMA16(ah[s], wl_[t][s], acc[t]);
#pragma unroll
                for (int t = 0; t < 4; ++t) acc[t] = MFMA16(al[s], wh_[t][s], acc[t]);
            }
#pragma unroll
            for (int t = 0; t < 4; ++t)
#pragma unroll
                for (int rg = 0; rg < 4; ++rg) {
                    const int row = rbase + lrow4 + rg;
                    if (row < N) {
                        h[(size_t)row * DIM + lr + 16 * t] = acc[t][rg];
                        hb[(size_t)row * DIM + lr + 16 * t] = bf16rne(acc[t][rg]);
                    }
                }
        }
    } else {
        // ---------------- bin path ----------------
        const int tid = threadIdx.x;
        const int base = (blockIdx.x >> 1) * CHUNK;
        __shared__ int lcnt[NBUCK];
        __shared__ int lbase[NBUCK];
        lcnt[tid] = 0;
        __syncthreads();
        const int lim = min(CHUNK, E - base);
        if (lim == CHUNK && (E & 3) == 0) {
            int r[8];
            {
                const int4 a = *(reinterpret_cast<const int4*>(ei + base) + tid * 2);
                const int4 b = *(reinterpret_cast<const int4*>(ei + base) + tid * 2 + 1);
                r[0]=a.x; r[1]=a.y; r[2]=a.z; r[3]=a.w;
                r[4]=b.x; r[5]=b.y; r[6]=b.z; r[7]=b.w;
            }
#pragma unroll
            for (int i = 0; i < 8; ++i) atomicAdd(&lcnt[r[i] >> BSHIFT], 1);
            __syncthreads();
            const int c = lcnt[tid];
            lbase[tid] = c ? atomicAdd(&bcursor[tid], c) : 0;
            lcnt[tid] = 0;
            __syncthreads();
            int cc[8], ss[8];
            {
                const int4 a = *(reinterpret_cast<const int4*>(ei + E + base) + tid * 2);
                const int4 b = *(reinterpret_cast<const int4*>(ei + E + base) + tid * 2 + 1);
                cc[0]=a.x; cc[1]=a.y; cc[2]=a.z; cc[3]=a.w;
                cc[4]=b.x; cc[5]=b.y; cc[6]=b.z; cc[7]=b.w;
                const int4 s2 = *(reinterpret_cast<const int4*>(sgn + base) + tid * 2);
                const int4 s3 = *(reinterpret_cast<const int4*>(sgn + base) + tid * 2 + 1);
                ss[0]=s2.x; ss[1]=s2.y; ss[2]=s2.z; ss[3]=s2.w;
                ss[4]=s3.x; ss[5]=s3.y; ss[6]=s3.z; ss[7]=s3.w;
            }
#pragma unroll
            for (int i = 0; i < 8; ++i) {
                const int bkt = r[i] >> BSHIFT;
                const int idx = lbase[bkt] + atomicAdd(&lcnt[bkt], 1);
                if (idx < BCAP)
                    records[bkt * BCAP + idx] = cc[i] | (ss[i] << 17) | ((r[i] & 511) << 18);
            }
        } else {
            for (int k = tid; k < lim; k += 256)
                atomicAdd(&lcnt[ei[base + k] >> BSHIFT], 1);
            __syncthreads();
            const int c = lcnt[tid];
            lbase[tid] = c ? atomicAdd(&bcursor[tid], c) : 0;
            lcnt[tid] = 0;
            __syncthreads();
            for (int k = tid; k < lim; k += 256) {
                const int e = base + k;
                const int rr = ei[e];
                const int cc2 = ei[E + e];
                const int s = sgn[e];
                const int b = rr >> BSHIFT;
                const int idx = lbase[b] + atomicAdd(&lcnt[b], 1);
                if (idx < BCAP)
                    records[b * BCAP + idx] = cc2 | (s << 17) | ((rr & 511) << 18);
            }
        }
    }
}

__device__ __forceinline__ int wave_incl_scan(int v, int lane) {
#pragma unroll
    for (int off = 1; off < 64; off <<= 1) {
        int t = __shfl_up(v, (unsigned)off, 64);
        if (lane >= off) v += t;
    }
    return v;
}

// One WG per bucket. Redundant in-block scan of bcursor replaces scan256.
__global__ __launch_bounds__(256) void build_kernel(
    const int* __restrict__ records, const int* __restrict__ bcursor,
    int* __restrict__ offsets, int* __restrict__ edata, int N)
{
    const int b = blockIdx.x;
    const int tid = threadIdx.x, lane = tid & 63, w = tid >> 6;
    const int nbase = b << BSHIFT;
    const int nn = min(512, N - nbase);
    if (nn <= 0) return;

    __shared__ int ncnt[512];
    __shared__ int wtot[8];
    __shared__ int csrb_l[NBUCK];
    __shared__ int stag[BCAP];

    // in-block exclusive scan of bucket counts -> this bucket's CSR base
    {
        const int bv = min(bcursor[tid], BCAP);
        const int inc = wave_incl_scan(bv, lane);
        if (lane == 63) wtot[w] = inc;
        __syncthreads();
        int add = 0;
#pragma unroll
        for (int i = 0; i < 4; ++i)
            if (i < w) add += wtot[i];
        csrb_l[tid] = add + inc - bv;
        __syncthreads();
    }
    const int base_csr = csrb_l[b];
    const int cnt = min(bcursor[b], BCAP);
    const int* rec = records + b * BCAP;

    ncnt[tid] = 0; ncnt[256 + tid] = 0;
    __syncthreads();
    for (int i = tid; i < cnt; i += 256)
        atomicAdd(&ncnt[rec[i] >> 18], 1);
    __syncthreads();
    const int v0 = ncnt[tid], v1 = ncnt[256 + tid];
    const int i0 = wave_incl_scan(v0, lane);
    if (lane == 63) wtot[w] = i0;
    const int i1 = wave_incl_scan(v1, lane);
    if (lane == 63) wtot[4 + w] = i1;
    __syncthreads();
    int a0 = 0, a1 = 0;
#pragma unroll
    for (int i = 0; i < 4; ++i) {
        if (i < w) { a0 += wtot[i]; a1 += wtot[4 + i]; }
    }
    const int half = wtot[0] + wtot[1] + wtot[2] + wtot[3];
    const int e0 = a0 + i0 - v0;
    const int e1 = half + a1 + i1 - v1;
    if (tid < nn)       offsets[nbase + tid]       = base_csr + e0;
    if (256 + tid < nn) offsets[nbase + 256 + tid] = base_csr + e1;
    __syncthreads();
    ncnt[tid] = e0; ncnt[256 + tid] = e1;
    __syncthreads();
    for (int i = tid; i < cnt; i += 256) {
        const int rcd = rec[i];
        const int p = atomicAdd(&ncnt[rcd >> 18], 1);
        stag[p] = (rcd & 0x1FFFF) | (((rcd >> 17) & 1) << 20);
    }
    __syncthreads();
    for (int i = tid; i < cnt; i += 256)
        edata[base_csr + i] = stag[i];
}

// 4 nodes/wave, 16 lanes/node, bf16 gathers; 32-bit saddr offsets; 8-deep
// unroll; out-of-segment slots gather hb row 0 (hot line) via cndmask.
__global__ __launch_bounds__(256) void attn_kernel(
    const float* __restrict__ h, const unsigned short* __restrict__ hb,
    const int* __restrict__ offsets, const int* __restrict__ edata,
    const float* __restrict__ sign_tab, float* __restrict__ aggr, int n)
{
    const int lane = threadIdx.x & 63;
    const int gl   = lane & 15;
    const int node = blockIdx.x * 16 + ((threadIdx.x >> 6) << 2) + (lane >> 4);
    const bool alive = node < n;
    const int nidx = alive ? node : 0;

    const int beg = offsets[nidx];
    const int deg = offsets[nidx + 1] - beg;

    const float4 hi = *reinterpret_cast<const float4*>(h + ((unsigned)nidx << 6) + (gl << 2));
    const float4 s0 = *reinterpret_cast<const float4*>(sign_tab + ((gl & 3) << 2));
    const float4 s1 = *reinterpret_cast<const float4*>(sign_tab + 16 + ((gl & 3) << 2));
    const f32x2v hs0a = {hi.x * s0.x, hi.y * s0.y};
    const f32x2v hs0b = {hi.z * s0.z, hi.w * s0.w};
    const f32x2v hs1a = {hi.x * s1.x, hi.y * s1.y};
    const f32x2v hs1b = {hi.z * s1.z, hi.w * s1.w};

    int maxdeg = max(deg, __shfl_xor(deg, 16, 64));
    maxdeg = max(maxdeg, __shfl_xor(maxdeg, 32, 64));

    float den = 0.f;
    f32x2v ma = {0.f, 0.f}, mb = {0.f, 0.f};
    const unsigned glb = (unsigned)(gl << 3);   // byte offset within a 128B row

    for (int e = 0; e < maxdeg; e += 8) {
        int pk[8];
#pragma unroll
        for (int u = 0; u < 8; ++u)
            pk[u] = edata[(unsigned)(beg + e + u)];
        uint2 v[8];
#pragma unroll
        for (int u = 0; u < 8; ++u) {
            unsigned off = (((unsigned)pk[u] & 0x1FFFFu) << 7) + glb;
            off = (e + u < deg) ? off : glb;   // junk slots hit row 0 (hot)
            v[u] = *reinterpret_cast<const uint2*>(
                reinterpret_cast<const char*>(hb) + off);
        }
#pragma unroll
        for (int u = 0; u < 8; ++u) {
            const f32x2v ha = {__uint_as_float(v[u].x << 16),
                               __uint_as_float(v[u].x & 0xFFFF0000u)};
            const f32x2v hc = {__uint_as_float(v[u].y << 16),
                               __uint_as_float(v[u].y & 0xFFFF0000u)};
            const bool sg = (pk[u] >> 20) & 1;
            const f32x2v wa = sg ? hs1a : hs0a;
            const f32x2v wb = sg ? hs1b : hs0b;
            const f32x2v p = wa * ha + wb * hc;
            float sc = p.x + p.y;
            sc += qperm<0xB1>(sc);
            sc += qperm<0x4E>(sc);
            const float ex = (e + u < deg) ? __expf(sc) : 0.f;
            den += ex;
            ma += ex * ha;
            mb += ex * hc;
        }
    }

    if (alive) {
        const float inv = 1.0f / (den + 1e-16f);
        float4 o = make_float4(ma.x * inv, ma.y * inv, mb.x * inv, mb.y * inv);
        *reinterpret_cast<float4*>(aggr + ((unsigned)node << 6) + (gl << 2)) = o;
    }
}

// fused tail via split-bf16 MFMA
__global__ __launch_bounds__(256, 2) void tail_kernel(
    const float* __restrict__ aggr, const float* __restrict__ hres,
    const short8* __restrict__ wf,
    const float* __restrict__ bh, const float* __restrict__ b1,
    const float* __restrict__ b2, const float* __restrict__ eps,
    float* __restrict__ out, int N)
{
    __shared__ float zb[4][16 * 68];
    const int l = threadIdx.x & 63;
    const int w = threadIdx.x >> 6;
    const int gw = blockIdx.x * 4 + w;
    const int nw = gridDim.x * 4;
    const int nstrips = (N + 15) >> 4;
    const int lr = l & 15, lk = (l >> 4) * 8, lrow4 = (l >> 4) * 4;
    float* zw = zb[w];

    short8 whh[4][2], w1h[4][2], w2h[4][2];
#pragma unroll
    for (int t = 0; t < 4; ++t)
#pragma unroll
        for (int s = 0; s < 2; ++s) {
            whh[t][s] = wf[(((1 * 4 + t) * 2 + s) * 2 + 0) * 64 + l];
            w1h[t][s] = wf[(((2 * 4 + t) * 2 + s) * 2 + 0) * 64 + l];
            w2h[t][s] = wf[(((3 * 4 + t) * 2 + s) * 2 + 0) * 64 + l];
        }
    float bh4[4], b14[4], b24[4];
#pragma unroll
    for (int t = 0; t < 4; ++t) {
        bh4[t] = bh[lr + 16 * t];
        b14[t] = b1[lr + 16 * t];
        b24[t] = b2[lr + 16 * t];
    }
    const float escale = 1.0f + eps[0];

    for (int strip = gw; strip < nstrips; strip += nw) {
        const int rbase = strip * 16;

        float vh[4][4];
#pragma unroll
        for (int t = 0; t < 4; ++t)
#pragma unroll
            for (int rg = 0; rg < 4; ++rg)
                vh[t][rg] = hres[(size_t)min(rbase + lrow4 + rg, N - 1) * DIM + lr + 16 * t];

        // ---- stage 1: aggr @ Wh^T ----
        const int arow = min(rbase + lr, N - 1);
        short8 ah[2], al[2];
#pragma unroll
        for (int s = 0; s < 2; ++s) {
            const float4 p0 = *reinterpret_cast<const float4*>(aggr + (size_t)arow * DIM + 32 * s + lk);
            const float4 p1 = *reinterpret_cast<const float4*>(aggr + (size_t)arow * DIM + 32 * s + lk + 4);
            float f[8] = {p0.x, p0.y, p0.z, p0.w, p1.x, p1.y, p1.z, p1.w};
            cvt8(f, ah[s], al[s]);
        }
        short8 lo_[4][2];
#pragma unroll
        for (int t = 0; t < 4; ++t)
#pragma unroll
            for (int s = 0; s < 2; ++s)
                lo_[t][s] = wf[(((1 * 4 + t) * 2 + s) * 2 + 1) * 64 + l];
        f32x4 acc[4];
#pragma unroll
        for (int t = 0; t < 4; ++t) acc[t] = (f32x4){bh4[t], bh4[t], bh4[t], bh4[t]};
#pragma unroll
        for (int s = 0; s < 2; ++s) {
#pragma unroll
            for (int t = 0; t < 4; ++t) acc[t] = MFMA16(ah[s], whh[t][s], acc[t]);
#pragma unroll
            for (int t = 0; t < 4; ++t) acc[t] = MFMA16(ah[s], lo_[t][s], acc[t]);
#pragma unroll
            for (int t = 0; t < 4; ++t) acc[t] = MFMA16(al[s], whh[t][s], acc[t]);
        }
#pragma unroll
        for (int t = 0; t < 4; ++t)
#pragma unroll
            for (int rg = 0; rg < 4; ++rg)
                zw[(lrow4 + rg) * 68 + lr + 16 * t] = fmaf(escale, vh[t][rg], acc[t][rg]);
        asm volatile("s_waitcnt lgkmcnt(0)" ::: "memory");

        // ---- stage 2: z @ W1^T, relu ----
        short8 zh[2], zl[2];
#pragma unroll
        for (int s = 0; s < 2; ++s) {
            const float4 q0 = *reinterpret_cast<const float4*>(zw + lr * 68 + 32 * s + lk);
            const float4 q1 = *reinterpret_cast<const float4*>(zw + lr * 68 + 32 * s + lk + 4);
            float f[8] = {q0.x, q0.y, q0.z, q0.w, q1.x, q1.y, q1.z, q1.w};
            cvt8(f, zh[s], zl[s]);
        }
#pragma unroll
        for (int t = 0; t < 4; ++t)
#pragma unroll
            for (int s = 0; s < 2; ++s)
                lo_[t][s] = wf[(((2 * 4 + t) * 2 + s) * 2 + 1) * 64 + l];
#pragma unroll
        for (int t = 0; t < 4; ++t) acc[t] = (f32x4){b14[t], b14[t], b14[t], b14[t]};
#pragma unroll
        for (int s = 0; s < 2; ++s) {
#pragma unroll
            for (int t = 0; t < 4; ++t) acc[t] = MFMA16(zh[s], w1h[t][s], acc[t]);
#pragma unroll
            for (int t = 0; t < 4; ++t) acc[t] = MFMA16(zh[s], lo_[t][s], acc[t]);
#pragma unroll
            for (int t = 0; t < 4; ++t) acc[t] = MFMA16(zl[s], w1h[t][s], acc[t]);
        }
#pragma unroll
        for (int t = 0; t < 4; ++t)
#pragma unroll
            for (int rg = 0; rg < 4; ++rg)
                zw[(lrow4 + rg) * 68 + lr + 16 * t] = fmaxf(acc[t][rg], 0.f);
        asm volatile("s_waitcnt lgkmcnt(0)" ::: "memory");

        // ---- stage 3: hid @ W2^T ----
        short8 hh[2], hl[2];
#pragma unroll
        for (int s = 0; s < 2; ++s) {
            const float4 q0 = *reinterpret_cast<const float4*>(zw + lr * 68 + 32 * s + lk);
            const float4 q1 = *reinterpret_cast<const float4*>(zw + lr * 68 + 32 * s + lk + 4);
            float f[8] = {q0.x, q0.y, q0.z, q0.w, q1.x, q1.y, q1.z, q1.w};
            cvt8(f, hh[s], hl[s]);
        }
#pragma unroll
        for (int t = 0; t < 4; ++t)
#pragma unroll
            for (int s = 0; s < 2; ++s)
                lo_[t][s] = wf[(((3 * 4 + t) * 2 + s) * 2 + 1) * 64 + l];
#pragma unroll
        for (int t = 0; t < 4; ++t) acc[t] = (f32x4){b24[t], b24[t], b24[t], b24[t]};
#pragma unroll
        for (int s = 0; s < 2; ++s) {
#pragma unroll
            for (int t = 0; t < 4; ++t) acc[t] = MFMA16(hh[s], w2h[t][s], acc[t]);
#pragma unroll
            for (int t = 0; t < 4; ++t) acc[t] = MFMA16(hh[s], lo_[t][s], acc[t]);
#pragma unroll
            for (int t = 0; t < 4; ++t) acc[t] = MFMA16(hl[s], w2h[t][s], acc[t]);
        }
#pragma unroll
        for (int t = 0; t < 4; ++t)
#pragma unroll
            for (int rg = 0; rg < 4; ++rg) {
                const int row = rbase + lrow4 + rg;
                if (row < N) out[(size_t)row * DIM + lr + 16 * t] = acc[t][rg];
            }
    }
}

extern "C" void kernel_launch(void* const* d_in, const int* in_sizes, int n_in,
                              void* d_out, int out_size, void* d_ws, size_t ws_size,
                              hipStream_t stream) {
    const float* x        = (const float*)d_in[0];
    const int*   ei       = (const int*)d_in[1];
    const int*   esign    = (const int*)d_in[2];
    const float* Wl_w     = (const float*)d_in[3];
    const float* Wl_b     = (const float*)d_in[4];
    const float* sign_tab = (const float*)d_in[5];
    const float* Wh_w     = (const float*)d_in[6];
    const float* Wh_b     = (const float*)d_in[7];
    const float* w1       = (const float*)d_in[8];
    const float* b1       = (const float*)d_in[9];
    const float* w2       = (const float*)d_in[10];
    const float* b2       = (const float*)d_in[11];
    const float* eps      = (const float*)d_in[12];
    float* out = (float*)d_out;

    const int N = in_sizes[0] / DIM;
    const int E = in_sizes[2];

    float* h       = (float*)d_ws;
    float* aggr    = h + (size_t)N * DIM;
    int*   records = (int*)aggr;                 // alias: dead before attn writes aggr
    int*   edata   = (int*)(aggr + (size_t)N * DIM);
    int*   bcursor = edata + (E + 520);          // 512 sentinel slots + slack
    int*   offsets = bcursor + NBUCK;            // N+1 ints
    short8* wf     = (short8*)(offsets + ((N + 1 + 3) & ~3));  // 16KB, 16B-aligned
    unsigned short* hb = (unsigned short*)d_out; // bf16 mirror: d_out is dead
                                                 // scratch until tail overwrites it

    const int NB = (E + CHUNK - 1) / CHUNK;

    // frag prep + bcursor zero + edata sentinels + offsets[N]
    prep_kernel<<<1, 256, 0, stream>>>(Wl_w, Wh_w, w1, w2, wf, bcursor,
                                       edata, offsets, N, E);

    // fused: h-projection GEMM (odd blocks) || edge binning (even blocks)
    gemmbin_kernel<<<2 * NB, 256, 0, stream>>>(x, wf, Wl_b, h, hb, N,
                                               ei, esign, bcursor, records, E, NB);

    // per-bucket CSR finalize (in-block scan of bucket counts)
    build_kernel<<<NBUCK, 256, 0, stream>>>(records, bcursor, offsets, edata, N);

    // segment softmax + aggregation (bf16 gathers)
    attn_kernel<<<(N + 15) / 16, 256, 0, stream>>>(h, hb, offsets, edata, sign_tab, aggr, N);

    // fused tail (MFMA): z -> relu mlp -> out
    tail_kernel<<<512, 256, 0, stream>>>(aggr, h, wf, Wh_b, b1, b2, eps, out, N);
}

// Round 14
// 123.444 us; speedup vs baseline: 1.2749x; 1.0098x over previous
//
#include <hip/hip_runtime.h>

#define DIM 64
#define NBUCK 256
#define BSHIFT 9
#define BCAP 12288
#define CHUNK 4096

typedef __attribute__((ext_vector_type(4))) float f32x4;
typedef __attribute__((ext_vector_type(2))) float f32x2v;
typedef __attribute__((ext_vector_type(8))) short short8;

#define MFMA16(a, b, c) __builtin_amdgcn_mfma_f32_16x16x32_bf16(a, b, c, 0, 0, 0)

template <int CTRL>
__device__ __forceinline__ float qperm(float v) {
    return __int_as_float(__builtin_amdgcn_update_dpp(
        0, __float_as_int(v), CTRL, 0xF, 0xF, true));
}

// split fp32 -> bf16 hi + bf16 lo (truncation; dropped term ~2^-16 rel)
__device__ __forceinline__ void cvt8(const float* f, short8& hi, short8& lo) {
#pragma unroll
    for (int e = 0; e < 8; ++e) {
        const unsigned u = __float_as_uint(f[e]);
        hi[e] = (short)(u >> 16);
        const float hf = __uint_as_float(u & 0xFFFF0000u);
        lo[e] = (short)(__float_as_uint(f[e] - hf) >> 16);
    }
}

__device__ __forceinline__ unsigned short bf16rne(float f) {
    const unsigned u = __float_as_uint(f);
    return (unsigned short)((u + 0x7FFFu + ((u >> 16) & 1u)) >> 16);
}

// Weight fragments (hi/lo bf16, B-frag order); zero bcursor; edata sentinels;
// offsets[N]=E.
__global__ __launch_bounds__(256) void prep_kernel(
    const float* __restrict__ Wl, const float* __restrict__ Wh,
    const float* __restrict__ W1, const float* __restrict__ W2,
    short8* __restrict__ wf, int* __restrict__ bcursor,
    int* __restrict__ edata, int* __restrict__ offsets, int N, int E)
{
    const int tid = threadIdx.x;
    bcursor[tid] = 0;
    edata[E + tid] = 0;
    edata[E + 256 + tid] = 0;
    if (tid == 0) offsets[N] = E;
    const int m = tid >> 6, l = tid & 63;
    const float* W = (m == 0) ? Wl : (m == 1) ? Wh : (m == 2) ? W1 : W2;
    const int o = l & 15;
    const int kg = (l >> 4) * 8;
#pragma unroll
    for (int t = 0; t < 4; ++t)
#pragma unroll
        for (int s = 0; s < 2; ++s) {
            float f[8];
#pragma unroll
            for (int e = 0; e < 8; ++e)
                f[e] = W[(o + 16 * t) * DIM + 32 * s + kg + e];
            short8 hi, lo;
            cvt8(f, hi, lo);
            const int base = (((m * 4 + t) * 2 + s) * 2);
            wf[(base + 0) * 64 + l] = hi;
            wf[(base + 1) * 64 + l] = lo;
        }
}

// Fused: odd blocks = h-projection GEMM (MFMA); even blocks = edge binning.
// CHUNK=4096, 16 edges/thread: halves reserve-atomic chain vs 2048 (r13 lesson).
__global__ __launch_bounds__(256, 3) void gemmbin_kernel(
    const float* __restrict__ x, const short8* __restrict__ wf,
    const float* __restrict__ bias, float* __restrict__ h,
    unsigned short* __restrict__ hb, int N,
    const int* __restrict__ ei, const int* __restrict__ sgn,
    int* __restrict__ bcursor, int* __restrict__ records, int E, int NB)
{
    if (blockIdx.x & 1) {
        // ---------------- GEMM path ----------------
        const int l = threadIdx.x & 63;
        const int gw = (blockIdx.x >> 1) * 4 + (threadIdx.x >> 6);
        const int nw = NB * 4;
        const int nstrips = (N + 15) >> 4;
        const int lr = l & 15, lk = (l >> 4) * 8, lrow4 = (l >> 4) * 4;

        short8 wh_[4][2], wl_[4][2];
#pragma unroll
        for (int t = 0; t < 4; ++t)
#pragma unroll
            for (int s = 0; s < 2; ++s) {
                wh_[t][s] = wf[(((0 * 4 + t) * 2 + s) * 2 + 0) * 64 + l];
                wl_[t][s] = wf[(((0 * 4 + t) * 2 + s) * 2 + 1) * 64 + l];
            }
        float b4[4];
#pragma unroll
        for (int t = 0; t < 4; ++t) b4[t] = bias[lr + 16 * t];

        for (int strip = gw; strip < nstrips; strip += nw) {
            const int rbase = strip * 16;
            const int arow = min(rbase + lr, N - 1);
            short8 ah[2], al[2];
#pragma unroll
            for (int s = 0; s < 2; ++s) {
                const float4 p0 = *reinterpret_cast<const float4*>(x + (size_t)arow * DIM + 32 * s + lk);
                const float4 p1 = *reinterpret_cast<const float4*>(x + (size_t)arow * DIM + 32 * s + lk + 4);
                float f[8] = {p0.x, p0.y, p0.z, p0.w, p1.x, p1.y, p1.z, p1.w};
                cvt8(f, ah[s], al[s]);
            }
            f32x4 acc[4];
#pragma unroll
            for (int t = 0; t < 4; ++t) acc[t] = (f32x4){b4[t], b4[t], b4[t], b4[t]};
#pragma unroll
            for (int s = 0; s < 2; ++s) {
#pragma unroll
                for (int t = 0; t < 4; ++t) acc[t] = MFMA16(ah[s], wh_[t][s], acc[t]);
#pragma unroll
                for (int t = 0; t < 4; ++t) acc[t] = MFMA16(ah[s], wl_[t][s], acc[t]);
#pragma unroll
                for (int t = 0; t < 4; ++t) acc[t] = MFMA16(al[s], wh_[t][s], acc[t]);
            }
#pragma unroll
            for (int t = 0; t < 4; ++t)
#pragma unroll
                for (int rg = 0; rg < 4; ++rg) {
                    const int row = rbase + lrow4 + rg;
                    if (row < N) {
                        h[(size_t)row * DIM + lr + 16 * t] = acc[t][rg];
                        hb[(size_t)row * DIM + lr + 16 * t] = bf16rne(acc[t][rg]);
                    }
                }
        }
    } else {
        // ---------------- bin path (16 edges/thread) ----------------
        const int tid = threadIdx.x;
        const int base = (blockIdx.x >> 1) * CHUNK;
        __shared__ int lcnt[NBUCK];
        __shared__ int lbase[NBUCK];
        lcnt[tid] = 0;
        __syncthreads();
        const int lim = min(CHUNK, E - base);
        if (lim == CHUNK && (E & 3) == 0) {
            int r[16];
#pragma unroll
            for (int j = 0; j < 4; ++j) {
                const int4 a = *(reinterpret_cast<const int4*>(ei + base) + tid * 4 + j);
                r[4*j+0]=a.x; r[4*j+1]=a.y; r[4*j+2]=a.z; r[4*j+3]=a.w;
            }
#pragma unroll
            for (int i = 0; i < 16; ++i) atomicAdd(&lcnt[r[i] >> BSHIFT], 1);
            __syncthreads();
            const int c = lcnt[tid];
            lbase[tid] = c ? atomicAdd(&bcursor[tid], c) : 0;
            lcnt[tid] = 0;
            __syncthreads();
            int cc[16], ss[16];
#pragma unroll
            for (int j = 0; j < 4; ++j) {
                const int4 a = *(reinterpret_cast<const int4*>(ei + E + base) + tid * 4 + j);
                cc[4*j+0]=a.x; cc[4*j+1]=a.y; cc[4*j+2]=a.z; cc[4*j+3]=a.w;
                const int4 s2 = *(reinterpret_cast<const int4*>(sgn + base) + tid * 4 + j);
                ss[4*j+0]=s2.x; ss[4*j+1]=s2.y; ss[4*j+2]=s2.z; ss[4*j+3]=s2.w;
            }
#pragma unroll
            for (int i = 0; i < 16; ++i) {
                const int bkt = r[i] >> BSHIFT;
                const int idx = lbase[bkt] + atomicAdd(&lcnt[bkt], 1);
                if (idx < BCAP)
                    records[bkt * BCAP + idx] = cc[i] | (ss[i] << 17) | ((r[i] & 511) << 18);
            }
        } else {
            for (int k = tid; k < lim; k += 256)
                atomicAdd(&lcnt[ei[base + k] >> BSHIFT], 1);
            __syncthreads();
            const int c = lcnt[tid];
            lbase[tid] = c ? atomicAdd(&bcursor[tid], c) : 0;
            lcnt[tid] = 0;
            __syncthreads();
            for (int k = tid; k < lim; k += 256) {
                const int e = base + k;
                const int rr = ei[e];
                const int cc2 = ei[E + e];
                const int s = sgn[e];
                const int b = rr >> BSHIFT;
                const int idx = lbase[b] + atomicAdd(&lcnt[b], 1);
                if (idx < BCAP)
                    records[b * BCAP + idx] = cc2 | (s << 17) | ((rr & 511) << 18);
            }
        }
    }
}

__device__ __forceinline__ int wave_incl_scan(int v, int lane) {
#pragma unroll
    for (int off = 1; off < 64; off <<= 1) {
        int t = __shfl_up(v, (unsigned)off, 64);
        if (lane >= off) v += t;
    }
    return v;
}

// One WG per bucket. Redundant in-block scan of bcursor replaces scan256.
__global__ __launch_bounds__(256) void build_kernel(
    const int* __restrict__ records, const int* __restrict__ bcursor,
    int* __restrict__ offsets, int* __restrict__ edata, int N)
{
    const int b = blockIdx.x;
    const int tid = threadIdx.x, lane = tid & 63, w = tid >> 6;
    const int nbase = b << BSHIFT;
    const int nn = min(512, N - nbase);
    if (nn <= 0) return;

    __shared__ int ncnt[512];
    __shared__ int wtot[8];
    __shared__ int csrb_l[NBUCK];
    __shared__ int stag[BCAP];

    {
        const int bv = min(bcursor[tid], BCAP);
        const int inc = wave_incl_scan(bv, lane);
        if (lane == 63) wtot[w] = inc;
        __syncthreads();
        int add = 0;
#pragma unroll
        for (int i = 0; i < 4; ++i)
            if (i < w) add += wtot[i];
        csrb_l[tid] = add + inc - bv;
        __syncthreads();
    }
    const int base_csr = csrb_l[b];
    const int cnt = min(bcursor[b], BCAP);
    const int* rec = records + b * BCAP;

    ncnt[tid] = 0; ncnt[256 + tid] = 0;
    __syncthreads();
    for (int i = tid; i < cnt; i += 256)
        atomicAdd(&ncnt[rec[i] >> 18], 1);
    __syncthreads();
    const int v0 = ncnt[tid], v1 = ncnt[256 + tid];
    const int i0 = wave_incl_scan(v0, lane);
    if (lane == 63) wtot[w] = i0;
    const int i1 = wave_incl_scan(v1, lane);
    if (lane == 63) wtot[4 + w] = i1;
    __syncthreads();
    int a0 = 0, a1 = 0;
#pragma unroll
    for (int i = 0; i < 4; ++i) {
        if (i < w) { a0 += wtot[i]; a1 += wtot[4 + i]; }
    }
    const int half = wtot[0] + wtot[1] + wtot[2] + wtot[3];
    const int e0 = a0 + i0 - v0;
    const int e1 = half + a1 + i1 - v1;
    if (tid < nn)       offsets[nbase + tid]       = base_csr + e0;
    if (256 + tid < nn) offsets[nbase + 256 + tid] = base_csr + e1;
    __syncthreads();
    ncnt[tid] = e0; ncnt[256 + tid] = e1;
    __syncthreads();
    for (int i = tid; i < cnt; i += 256) {
        const int rcd = rec[i];
        const int p = atomicAdd(&ncnt[rcd >> 18], 1);
        stag[p] = (rcd & 0x1FFFF) | (((rcd >> 17) & 1) << 20);
    }
    __syncthreads();
    for (int i = tid; i < cnt; i += 256)
        edata[base_csr + i] = stag[i];
}

// 4 nodes/wave, 16 lanes/node, bf16 gathers; 32-bit saddr offsets; 8-deep
// unroll; out-of-segment slots gather hb row 0 (hot line) via cndmask.
__global__ __launch_bounds__(256) void attn_kernel(
    const float* __restrict__ h, const unsigned short* __restrict__ hb,
    const int* __restrict__ offsets, const int* __restrict__ edata,
    const float* __restrict__ sign_tab, float* __restrict__ aggr, int n)
{
    const int lane = threadIdx.x & 63;
    const int gl   = lane & 15;
    const int node = blockIdx.x * 16 + ((threadIdx.x >> 6) << 2) + (lane >> 4);
    const bool alive = node < n;
    const int nidx = alive ? node : 0;

    const int beg = offsets[nidx];
    const int deg = offsets[nidx + 1] - beg;

    const float4 hi = *reinterpret_cast<const float4*>(h + ((unsigned)nidx << 6) + (gl << 2));
    const float4 s0 = *reinterpret_cast<const float4*>(sign_tab + ((gl & 3) << 2));
    const float4 s1 = *reinterpret_cast<const float4*>(sign_tab + 16 + ((gl & 3) << 2));
    const f32x2v hs0a = {hi.x * s0.x, hi.y * s0.y};
    const f32x2v hs0b = {hi.z * s0.z, hi.w * s0.w};
    const f32x2v hs1a = {hi.x * s1.x, hi.y * s1.y};
    const f32x2v hs1b = {hi.z * s1.z, hi.w * s1.w};

    int maxdeg = max(deg, __shfl_xor(deg, 16, 64));
    maxdeg = max(maxdeg, __shfl_xor(maxdeg, 32, 64));

    float den = 0.f;
    f32x2v ma = {0.f, 0.f}, mb = {0.f, 0.f};
    const unsigned glb = (unsigned)(gl << 3);   // byte offset within a 128B row

    for (int e = 0; e < maxdeg; e += 8) {
        int pk[8];
#pragma unroll
        for (int u = 0; u < 8; ++u)
            pk[u] = edata[(unsigned)(beg + e + u)];
        uint2 v[8];
#pragma unroll
        for (int u = 0; u < 8; ++u) {
            unsigned off = (((unsigned)pk[u] & 0x1FFFFu) << 7) + glb;
            off = (e + u < deg) ? off : glb;   // junk slots hit row 0 (hot)
            v[u] = *reinterpret_cast<const uint2*>(
                reinterpret_cast<const char*>(hb) + off);
        }
#pragma unroll
        for (int u = 0; u < 8; ++u) {
            const f32x2v ha = {__uint_as_float(v[u].x << 16),
                               __uint_as_float(v[u].x & 0xFFFF0000u)};
            const f32x2v hc = {__uint_as_float(v[u].y << 16),
                               __uint_as_float(v[u].y & 0xFFFF0000u)};
            const bool sg = (pk[u] >> 20) & 1;
            const f32x2v wa = sg ? hs1a : hs0a;
            const f32x2v wb = sg ? hs1b : hs0b;
            const f32x2v p = wa * ha + wb * hc;
            float sc = p.x + p.y;
            sc += qperm<0xB1>(sc);
            sc += qperm<0x4E>(sc);
            const float ex = (e + u < deg) ? __expf(sc) : 0.f;
            den += ex;
            ma += ex * ha;
            mb += ex * hc;
        }
    }

    if (alive) {
        const float inv = 1.0f / (den + 1e-16f);
        float4 o = make_float4(ma.x * inv, ma.y * inv, mb.x * inv, mb.y * inv);
        *reinterpret_cast<float4*>(aggr + ((unsigned)node << 6) + (gl << 2)) = o;
    }
}

// fused tail via split-bf16 MFMA
__global__ __launch_bounds__(256, 2) void tail_kernel(
    const float* __restrict__ aggr, const float* __restrict__ hres,
    const short8* __restrict__ wf,
    const float* __restrict__ bh, const float* __restrict__ b1,
    const float* __restrict__ b2, const float* __restrict__ eps,
    float* __restrict__ out, int N)
{
    __shared__ float zb[4][16 * 68];
    const int l = threadIdx.x & 63;
    const int w = threadIdx.x >> 6;
    const int gw = blockIdx.x * 4 + w;
    const int nw = gridDim.x * 4;
    const int nstrips = (N + 15) >> 4;
    const int lr = l & 15, lk = (l >> 4) * 8, lrow4 = (l >> 4) * 4;
    float* zw = zb[w];

    short8 whh[4][2], w1h[4][2], w2h[4][2];
#pragma unroll
    for (int t = 0; t < 4; ++t)
#pragma unroll
        for (int s = 0; s < 2; ++s) {
            whh[t][s] = wf[(((1 * 4 + t) * 2 + s) * 2 + 0) * 64 + l];
            w1h[t][s] = wf[(((2 * 4 + t) * 2 + s) * 2 + 0) * 64 + l];
            w2h[t][s] = wf[(((3 * 4 + t) * 2 + s) * 2 + 0) * 64 + l];
        }
    float bh4[4], b14[4], b24[4];
#pragma unroll
    for (int t = 0; t < 4; ++t) {
        bh4[t] = bh[lr + 16 * t];
        b14[t] = b1[lr + 16 * t];
        b24[t] = b2[lr + 16 * t];
    }
    const float escale = 1.0f + eps[0];

    for (int strip = gw; strip < nstrips; strip += nw) {
        const int rbase = strip * 16;

        float vh[4][4];
#pragma unroll
        for (int t = 0; t < 4; ++t)
#pragma unroll
            for (int rg = 0; rg < 4; ++rg)
                vh[t][rg] = hres[(size_t)min(rbase + lrow4 + rg, N - 1) * DIM + lr + 16 * t];

        // ---- stage 1: aggr @ Wh^T ----
        const int arow = min(rbase + lr, N - 1);
        short8 ah[2], al[2];
#pragma unroll
        for (int s = 0; s < 2; ++s) {
            const float4 p0 = *reinterpret_cast<const float4*>(aggr + (size_t)arow * DIM + 32 * s + lk);
            const float4 p1 = *reinterpret_cast<const float4*>(aggr + (size_t)arow * DIM + 32 * s + lk + 4);
            float f[8] = {p0.x, p0.y, p0.z, p0.w, p1.x, p1.y, p1.z, p1.w};
            cvt8(f, ah[s], al[s]);
        }
        short8 lo_[4][2];
#pragma unroll
        for (int t = 0; t < 4; ++t)
#pragma unroll
            for (int s = 0; s < 2; ++s)
                lo_[t][s] = wf[(((1 * 4 + t) * 2 + s) * 2 + 1) * 64 + l];
        f32x4 acc[4];
#pragma unroll
        for (int t = 0; t < 4; ++t) acc[t] = (f32x4){bh4[t], bh4[t], bh4[t], bh4[t]};
#pragma unroll
        for (int s = 0; s < 2; ++s) {
#pragma unroll
            for (int t = 0; t < 4; ++t) acc[t] = MFMA16(ah[s], whh[t][s], acc[t]);
#pragma unroll
            for (int t = 0; t < 4; ++t) acc[t] = MFMA16(ah[s], lo_[t][s], acc[t]);
#pragma unroll
            for (int t = 0; t < 4; ++t) acc[t] = MFMA16(al[s], whh[t][s], acc[t]);
        }
#pragma unroll
        for (int t = 0; t < 4; ++t)
#pragma unroll
            for (int rg = 0; rg < 4; ++rg)
                zw[(lrow4 + rg) * 68 + lr + 16 * t] = fmaf(escale, vh[t][rg], acc[t][rg]);
        asm volatile("s_waitcnt lgkmcnt(0)" ::: "memory");

        // ---- stage 2: z @ W1^T, relu ----
        short8 zh[2], zl[2];
#pragma unroll
        for (int s = 0; s < 2; ++s) {
            const float4 q0 = *reinterpret_cast<const float4*>(zw + lr * 68 + 32 * s + lk);
            const float4 q1 = *reinterpret_cast<const float4*>(zw + lr * 68 + 32 * s + lk + 4);
            float f[8] = {q0.x, q0.y, q0.z, q0.w, q1.x, q1.y, q1.z, q1.w};
            cvt8(f, zh[s], zl[s]);
        }
#pragma unroll
        for (int t = 0; t < 4; ++t)
#pragma unroll
            for (int s = 0; s < 2; ++s)
                lo_[t][s] = wf[(((2 * 4 + t) * 2 + s) * 2 + 1) * 64 + l];
#pragma unroll
        for (int t = 0; t < 4; ++t) acc[t] = (f32x4){b14[t], b14[t], b14[t], b14[t]};
#pragma unroll
        for (int s = 0; s < 2; ++s) {
#pragma unroll
            for (int t = 0; t < 4; ++t) acc[t] = MFMA16(zh[s], w1h[t][s], acc[t]);
#pragma unroll
            for (int t = 0; t < 4; ++t) acc[t] = MFMA16(zh[s], lo_[t][s], acc[t]);
#pragma unroll
            for (int t = 0; t < 4; ++t) acc[t] = MFMA16(zl[s], w1h[t][s], acc[t]);
        }
#pragma unroll
        for (int t = 0; t < 4; ++t)
#pragma unroll
            for (int rg = 0; rg < 4; ++rg)
                zw[(lrow4 + rg) * 68 + lr + 16 * t] = fmaxf(acc[t][rg], 0.f);
        asm volatile("s_waitcnt lgkmcnt(0)" ::: "memory");

        // ---- stage 3: hid @ W2^T ----
        short8 hh[2], hl[2];
#pragma unroll
        for (int s = 0; s < 2; ++s) {
            const float4 q0 = *reinterpret_cast<const float4*>(zw + lr * 68 + 32 * s + lk);
            const float4 q1 = *reinterpret_cast<const float4*>(zw + lr * 68 + 32 * s + lk + 4);
            float f[8] = {q0.x, q0.y, q0.z, q0.w, q1.x, q1.y, q1.z, q1.w};
            cvt8(f, hh[s], hl[s]);
        }
#pragma unroll
        for (int t = 0; t < 4; ++t)
#pragma unroll
            for (int s = 0; s < 2; ++s)
                lo_[t][s] = wf[(((3 * 4 + t) * 2 + s) * 2 + 1) * 64 + l];
#pragma unroll
        for (int t = 0; t < 4; ++t) acc[t] = (f32x4){b24[t], b24[t], b24[t], b24[t]};
#pragma unroll
        for (int s = 0; s < 2; ++s) {
#pragma unroll
            for (int t = 0; t < 4; ++t) acc[t] = MFMA16(hh[s], w2h[t][s], acc[t]);
#pragma unroll
            for (int t = 0; t < 4; ++t) acc[t] = MFMA16(hh[s], lo_[t][s], acc[t]);
#pragma unroll
            for (int t = 0; t < 4; ++t) acc[t] = MFMA16(hl[s], w2h[t][s], acc[t]);
        }
#pragma unroll
        for (int t = 0; t < 4; ++t)
#pragma unroll
            for (int rg = 0; rg < 4; ++rg) {
                const int row = rbase + lrow4 + rg;
                if (row < N) out[(size_t)row * DIM + lr + 16 * t] = acc[t][rg];
            }
    }
}

extern "C" void kernel_launch(void* const* d_in, const int* in_sizes, int n_in,
                              void* d_out, int out_size, void* d_ws, size_t ws_size,
                              hipStream_t stream) {
    const float* x        = (const float*)d_in[0];
    const int*   ei       = (const int*)d_in[1];
    const int*   esign    = (const int*)d_in[2];
    const float* Wl_w     = (const float*)d_in[3];
    const float* Wl_b     = (const float*)d_in[4];
    const float* sign_tab = (const float*)d_in[5];
    const float* Wh_w     = (const float*)d_in[6];
    const float* Wh_b     = (const float*)d_in[7];
    const float* w1       = (const float*)d_in[8];
    const float* b1       = (const float*)d_in[9];
    const float* w2       = (const float*)d_in[10];
    const float* b2       = (const float*)d_in[11];
    const float* eps      = (const float*)d_in[12];
    float* out = (float*)d_out;

    const int N = in_sizes[0] / DIM;
    const int E = in_sizes[2];

    float* h       = (float*)d_ws;
    float* aggr    = h + (size_t)N * DIM;
    int*   records = (int*)aggr;                 // alias: dead before attn writes aggr
    int*   edata   = (int*)(aggr + (size_t)N * DIM);
    int*   bcursor = edata + (E + 520);          // 512 sentinel slots + slack
    int*   offsets = bcursor + NBUCK;            // N+1 ints
    short8* wf     = (short8*)(offsets + ((N + 1 + 3) & ~3));  // 16KB, 16B-aligned
    unsigned short* hb = (unsigned short*)d_out; // bf16 mirror: d_out is dead
                                                 // scratch until tail overwrites it

    const int NB = (E + CHUNK - 1) / CHUNK;

    // frag prep + bcursor zero + edata sentinels + offsets[N]
    prep_kernel<<<1, 256, 0, stream>>>(Wl_w, Wh_w, w1, w2, wf, bcursor,
                                       edata, offsets, N, E);

    // fused: h-projection GEMM (odd blocks) || edge binning (even blocks)
    gemmbin_kernel<<<2 * NB, 256, 0, stream>>>(x, wf, Wl_b, h, hb, N,
                                               ei, esign, bcursor, records, E, NB);

    // per-bucket CSR finalize (in-block scan of bucket counts)
    build_kernel<<<NBUCK, 256, 0, stream>>>(records, bcursor, offsets, edata, N);

    // segment softmax + aggregation (bf16 gathers)
    attn_kernel<<<(N + 15) / 16, 256, 0, stream>>>(h, hb, offsets, edata, sign_tab, aggr, N);

    // fused tail (MFMA): z -> relu mlp -> out
    tail_kernel<<<512, 256, 0, stream>>>(aggr, h, wf, Wh_b, b1, b2, eps, out, N);
}

// Round 15
// 122.207 us; speedup vs baseline: 1.2878x; 1.0101x over previous
//
#include <hip/hip_runtime.h>

#define DIM 64
#define NBUCK 256
#define BSHIFT 9
#define BCAP 12288
#define CHUNK 4096

typedef __attribute__((ext_vector_type(4))) float f32x4;
typedef __attribute__((ext_vector_type(2))) float f32x2v;
typedef __attribute__((ext_vector_type(8))) short short8;

#define MFMA16(a, b, c) __builtin_amdgcn_mfma_f32_16x16x32_bf16(a, b, c, 0, 0, 0)

template <int CTRL>
__device__ __forceinline__ float qperm(float v) {
    return __int_as_float(__builtin_amdgcn_update_dpp(
        0, __float_as_int(v), CTRL, 0xF, 0xF, true));
}

// split fp32 -> bf16 hi + bf16 lo (truncation; dropped term ~2^-16 rel)
__device__ __forceinline__ void cvt8(const float* f, short8& hi, short8& lo) {
#pragma unroll
    for (int e = 0; e < 8; ++e) {
        const unsigned u = __float_as_uint(f[e]);
        hi[e] = (short)(u >> 16);
        const float hf = __uint_as_float(u & 0xFFFF0000u);
        lo[e] = (short)(__float_as_uint(f[e] - hf) >> 16);
    }
}

__device__ __forceinline__ unsigned short bf16rne(float f) {
    const unsigned u = __float_as_uint(f);
    return (unsigned short)((u + 0x7FFFu + ((u >> 16) & 1u)) >> 16);
}

// Weight fragments (hi/lo bf16, B-frag order); zero bcursor; edata sentinels;
// offsets[N]=E.
__global__ __launch_bounds__(256) void prep_kernel(
    const float* __restrict__ Wl, const float* __restrict__ Wh,
    const float* __restrict__ W1, const float* __restrict__ W2,
    short8* __restrict__ wf, int* __restrict__ bcursor,
    int* __restrict__ edata, int* __restrict__ offsets, int N, int E)
{
    const int tid = threadIdx.x;
    bcursor[tid] = 0;
    edata[E + tid] = 0;
    edata[E + 256 + tid] = 0;
    if (tid == 0) offsets[N] = E;
    const int m = tid >> 6, l = tid & 63;
    const float* W = (m == 0) ? Wl : (m == 1) ? Wh : (m == 2) ? W1 : W2;
    const int o = l & 15;
    const int kg = (l >> 4) * 8;
#pragma unroll
    for (int t = 0; t < 4; ++t)
#pragma unroll
        for (int s = 0; s < 2; ++s) {
            float f[8];
#pragma unroll
            for (int e = 0; e < 8; ++e)
                f[e] = W[(o + 16 * t) * DIM + 32 * s + kg + e];
            short8 hi, lo;
            cvt8(f, hi, lo);
            const int base = (((m * 4 + t) * 2 + s) * 2);
            wf[(base + 0) * 64 + l] = hi;
            wf[(base + 1) * 64 + l] = lo;
        }
}

// Fused: odd blocks = h-projection GEMM (MFMA); even blocks = edge binning.
// Phase-2 scatter: batched atomics-then-stores (MLP), branchless clamped idx.
__global__ __launch_bounds__(256, 3) void gemmbin_kernel(
    const float* __restrict__ x, const short8* __restrict__ wf,
    const float* __restrict__ bias, float* __restrict__ h,
    unsigned short* __restrict__ hb, int N,
    const int* __restrict__ ei, const int* __restrict__ sgn,
    int* __restrict__ bcursor, int* __restrict__ records, int E, int NB)
{
    if (blockIdx.x & 1) {
        // ---------------- GEMM path ----------------
        const int l = threadIdx.x & 63;
        const int gw = (blockIdx.x >> 1) * 4 + (threadIdx.x >> 6);
        const int nw = NB * 4;
        const int nstrips = (N + 15) >> 4;
        const int lr = l & 15, lk = (l >> 4) * 8, lrow4 = (l >> 4) * 4;

        short8 wh_[4][2], wl_[4][2];
#pragma unroll
        for (int t = 0; t < 4; ++t)
#pragma unroll
            for (int s = 0; s < 2; ++s) {
                wh_[t][s] = wf[(((0 * 4 + t) * 2 + s) * 2 + 0) * 64 + l];
                wl_[t][s] = wf[(((0 * 4 + t) * 2 + s) * 2 + 1) * 64 + l];
            }
        float b4[4];
#pragma unroll
        for (int t = 0; t < 4; ++t) b4[t] = bias[lr + 16 * t];

        for (int strip = gw; strip < nstrips; strip += nw) {
            const int rbase = strip * 16;
            const int arow = min(rbase + lr, N - 1);
            short8 ah[2], al[2];
#pragma unroll
            for (int s = 0; s < 2; ++s) {
                const float4 p0 = *reinterpret_cast<const float4*>(x + (size_t)arow * DIM + 32 * s + lk);
                const float4 p1 = *reinterpret_cast<const float4*>(x + (size_t)arow * DIM + 32 * s + lk + 4);
                float f[8] = {p0.x, p0.y, p0.z, p0.w, p1.x, p1.y, p1.z, p1.w};
                cvt8(f, ah[s], al[s]);
            }
            f32x4 acc[4];
#pragma unroll
            for (int t = 0; t < 4; ++t) acc[t] = (f32x4){b4[t], b4[t], b4[t], b4[t]};
#pragma unroll
            for (int s = 0; s < 2; ++s) {
#pragma unroll
                for (int t = 0; t < 4; ++t) acc[t] = MFMA16(ah[s], wh_[t][s], acc[t]);
#pragma unroll
                for (int t = 0; t < 4; ++t) acc[t] = MFMA16(ah[s], wl_[t][s], acc[t]);
#pragma unroll
                for (int t = 0; t < 4; ++t) acc[t] = MFMA16(al[s], wh_[t][s], acc[t]);
            }
#pragma unroll
            for (int t = 0; t < 4; ++t)
#pragma unroll
                for (int rg = 0; rg < 4; ++rg) {
                    const int row = rbase + lrow4 + rg;
                    if (row < N) {
                        h[(size_t)row * DIM + lr + 16 * t] = acc[t][rg];
                        hb[(size_t)row * DIM + lr + 16 * t] = bf16rne(acc[t][rg]);
                    }
                }
        }
    } else {
        // ---------------- bin path (16 edges/thread) ----------------
        const int tid = threadIdx.x;
        const int base = (blockIdx.x >> 1) * CHUNK;
        __shared__ int lcnt[NBUCK];
        __shared__ int lbase[NBUCK];
        lcnt[tid] = 0;
        __syncthreads();
        const int lim = min(CHUNK, E - base);
        if (lim == CHUNK && (E & 3) == 0) {
            int r[16];
#pragma unroll
            for (int j = 0; j < 4; ++j) {
                const int4 a = *(reinterpret_cast<const int4*>(ei + base) + tid * 4 + j);
                r[4*j+0]=a.x; r[4*j+1]=a.y; r[4*j+2]=a.z; r[4*j+3]=a.w;
            }
#pragma unroll
            for (int i = 0; i < 16; ++i) atomicAdd(&lcnt[r[i] >> BSHIFT], 1);
            __syncthreads();
            const int c = lcnt[tid];
            lbase[tid] = c ? atomicAdd(&bcursor[tid], c) : 0;
            lcnt[tid] = 0;
            __syncthreads();
            int cc[16], ss[16];
#pragma unroll
            for (int j = 0; j < 4; ++j) {
                const int4 a = *(reinterpret_cast<const int4*>(ei + E + base) + tid * 4 + j);
                cc[4*j+0]=a.x; cc[4*j+1]=a.y; cc[4*j+2]=a.z; cc[4*j+3]=a.w;
                const int4 s2 = *(reinterpret_cast<const int4*>(sgn + base) + tid * 4 + j);
                ss[4*j+0]=s2.x; ss[4*j+1]=s2.y; ss[4*j+2]=s2.z; ss[4*j+3]=s2.w;
            }
            // batched: 8 independent atomics, then 8 branchless stores
#pragma unroll
            for (int half = 0; half < 2; ++half) {
                int idx[8];
#pragma unroll
                for (int i = 0; i < 8; ++i) {
                    const int e8 = half * 8 + i;
                    const int bkt = r[e8] >> BSHIFT;
                    idx[i] = lbase[bkt] + atomicAdd(&lcnt[bkt], 1);
                }
#pragma unroll
                for (int i = 0; i < 8; ++i) {
                    const int e8 = half * 8 + i;
                    const int bkt = r[e8] >> BSHIFT;
                    records[bkt * BCAP + min(idx[i], BCAP - 1)] =
                        cc[e8] | (ss[e8] << 17) | ((r[e8] & 511) << 18);
                }
            }
        } else {
            for (int k = tid; k < lim; k += 256)
                atomicAdd(&lcnt[ei[base + k] >> BSHIFT], 1);
            __syncthreads();
            const int c = lcnt[tid];
            lbase[tid] = c ? atomicAdd(&bcursor[tid], c) : 0;
            lcnt[tid] = 0;
            __syncthreads();
            for (int k = tid; k < lim; k += 256) {
                const int e = base + k;
                const int rr = ei[e];
                const int cc2 = ei[E + e];
                const int s = sgn[e];
                const int b = rr >> BSHIFT;
                const int idx = min(lbase[b] + atomicAdd(&lcnt[b], 1), BCAP - 1);
                records[b * BCAP + idx] = cc2 | (s << 17) | ((rr & 511) << 18);
            }
        }
    }
}

__device__ __forceinline__ int wave_incl_scan(int v, int lane) {
#pragma unroll
    for (int off = 1; off < 64; off <<= 1) {
        int t = __shfl_up(v, (unsigned)off, 64);
        if (lane >= off) v += t;
    }
    return v;
}

// One WG per bucket. Redundant in-block scan of bcursor replaces scan256.
__global__ __launch_bounds__(256) void build_kernel(
    const int* __restrict__ records, const int* __restrict__ bcursor,
    int* __restrict__ offsets, int* __restrict__ edata, int N)
{
    const int b = blockIdx.x;
    const int tid = threadIdx.x, lane = tid & 63, w = tid >> 6;
    const int nbase = b << BSHIFT;
    const int nn = min(512, N - nbase);
    if (nn <= 0) return;

    __shared__ int ncnt[512];
    __shared__ int wtot[8];
    __shared__ int csrb_l[NBUCK];
    __shared__ int stag[BCAP];

    {
        const int bv = min(bcursor[tid], BCAP);
        const int inc = wave_incl_scan(bv, lane);
        if (lane == 63) wtot[w] = inc;
        __syncthreads();
        int add = 0;
#pragma unroll
        for (int i = 0; i < 4; ++i)
            if (i < w) add += wtot[i];
        csrb_l[tid] = add + inc - bv;
        __syncthreads();
    }
    const int base_csr = csrb_l[b];
    const int cnt = min(bcursor[b], BCAP);
    const int* rec = records + b * BCAP;

    ncnt[tid] = 0; ncnt[256 + tid] = 0;
    __syncthreads();
    for (int i = tid; i < cnt; i += 256)
        atomicAdd(&ncnt[rec[i] >> 18], 1);
    __syncthreads();
    const int v0 = ncnt[tid], v1 = ncnt[256 + tid];
    const int i0 = wave_incl_scan(v0, lane);
    if (lane == 63) wtot[w] = i0;
    const int i1 = wave_incl_scan(v1, lane);
    if (lane == 63) wtot[4 + w] = i1;
    __syncthreads();
    int a0 = 0, a1 = 0;
#pragma unroll
    for (int i = 0; i < 4; ++i) {
        if (i < w) { a0 += wtot[i]; a1 += wtot[4 + i]; }
    }
    const int half = wtot[0] + wtot[1] + wtot[2] + wtot[3];
    const int e0 = a0 + i0 - v0;
    const int e1 = half + a1 + i1 - v1;
    if (tid < nn)       offsets[nbase + tid]       = base_csr + e0;
    if (256 + tid < nn) offsets[nbase + 256 + tid] = base_csr + e1;
    __syncthreads();
    ncnt[tid] = e0; ncnt[256 + tid] = e1;
    __syncthreads();
    for (int i = tid; i < cnt; i += 256) {
        const int rcd = rec[i];
        const int p = atomicAdd(&ncnt[rcd >> 18], 1);
        stag[p] = (rcd & 0x1FFFF) | (((rcd >> 17) & 1) << 20);
    }
    __syncthreads();
    for (int i = tid; i < cnt; i += 256)
        edata[base_csr + i] = stag[i];
}

// 4 nodes/wave, 16 lanes/node, bf16 gathers; 32-bit saddr offsets; 8-deep
// unroll; out-of-segment slots gather hb row 0 (hot line) via cndmask.
__global__ __launch_bounds__(256) void attn_kernel(
    const float* __restrict__ h, const unsigned short* __restrict__ hb,
    const int* __restrict__ offsets, const int* __restrict__ edata,
    const float* __restrict__ sign_tab, float* __restrict__ aggr, int n)
{
    const int lane = threadIdx.x & 63;
    const int gl   = lane & 15;
    const int node = blockIdx.x * 16 + ((threadIdx.x >> 6) << 2) + (lane >> 4);
    const bool alive = node < n;
    const int nidx = alive ? node : 0;

    const int beg = offsets[nidx];
    const int deg = offsets[nidx + 1] - beg;

    const float4 hi = *reinterpret_cast<const float4*>(h + ((unsigned)nidx << 6) + (gl << 2));
    const float4 s0 = *reinterpret_cast<const float4*>(sign_tab + ((gl & 3) << 2));
    const float4 s1 = *reinterpret_cast<const float4*>(sign_tab + 16 + ((gl & 3) << 2));
    const f32x2v hs0a = {hi.x * s0.x, hi.y * s0.y};
    const f32x2v hs0b = {hi.z * s0.z, hi.w * s0.w};
    const f32x2v hs1a = {hi.x * s1.x, hi.y * s1.y};
    const f32x2v hs1b = {hi.z * s1.z, hi.w * s1.w};

    int maxdeg = max(deg, __shfl_xor(deg, 16, 64));
    maxdeg = max(maxdeg, __shfl_xor(maxdeg, 32, 64));

    float den = 0.f;
    f32x2v ma = {0.f, 0.f}, mb = {0.f, 0.f};
    const unsigned glb = (unsigned)(gl << 3);   // byte offset within a 128B row

    for (int e = 0; e < maxdeg; e += 8) {
        int pk[8];
#pragma unroll
        for (int u = 0; u < 8; ++u)
            pk[u] = edata[(unsigned)(beg + e + u)];
        uint2 v[8];
#pragma unroll
        for (int u = 0; u < 8; ++u) {
            unsigned off = (((unsigned)pk[u] & 0x1FFFFu) << 7) + glb;
            off = (e + u < deg) ? off : glb;   // junk slots hit row 0 (hot)
            v[u] = *reinterpret_cast<const uint2*>(
                reinterpret_cast<const char*>(hb) + off);
        }
#pragma unroll
        for (int u = 0; u < 8; ++u) {
            const f32x2v ha = {__uint_as_float(v[u].x << 16),
                               __uint_as_float(v[u].x & 0xFFFF0000u)};
            const f32x2v hc = {__uint_as_float(v[u].y << 16),
                               __uint_as_float(v[u].y & 0xFFFF0000u)};
            const bool sg = (pk[u] >> 20) & 1;
            const f32x2v wa = sg ? hs1a : hs0a;
            const f32x2v wb = sg ? hs1b : hs0b;
            const f32x2v p = wa * ha + wb * hc;
            float sc = p.x + p.y;
            sc += qperm<0xB1>(sc);
            sc += qperm<0x4E>(sc);
            const float ex = (e + u < deg) ? __expf(sc) : 0.f;
            den += ex;
            ma += ex * ha;
            mb += ex * hc;
        }
    }

    if (alive) {
        const float inv = 1.0f / (den + 1e-16f);
        float4 o = make_float4(ma.x * inv, ma.y * inv, mb.x * inv, mb.y * inv);
        *reinterpret_cast<float4*>(aggr + ((unsigned)node << 6) + (gl << 2)) = o;
    }
}

// fused tail via split-bf16 MFMA
__global__ __launch_bounds__(256, 2) void tail_kernel(
    const float* __restrict__ aggr, const float* __restrict__ hres,
    const short8* __restrict__ wf,
    const float* __restrict__ bh, const float* __restrict__ b1,
    const float* __restrict__ b2, const float* __restrict__ eps,
    float* __restrict__ out, int N)
{
    __shared__ float zb[4][16 * 68];
    const int l = threadIdx.x & 63;
    const int w = threadIdx.x >> 6;
    const int gw = blockIdx.x * 4 + w;
    const int nw = gridDim.x * 4;
    const int nstrips = (N + 15) >> 4;
    const int lr = l & 15, lk = (l >> 4) * 8, lrow4 = (l >> 4) * 4;
    float* zw = zb[w];

    short8 whh[4][2], w1h[4][2], w2h[4][2];
#pragma unroll
    for (int t = 0; t < 4; ++t)
#pragma unroll
        for (int s = 0; s < 2; ++s) {
            whh[t][s] = wf[(((1 * 4 + t) * 2 + s) * 2 + 0) * 64 + l];
            w1h[t][s] = wf[(((2 * 4 + t) * 2 + s) * 2 + 0) * 64 + l];
            w2h[t][s] = wf[(((3 * 4 + t) * 2 + s) * 2 + 0) * 64 + l];
        }
    float bh4[4], b14[4], b24[4];
#pragma unroll
    for (int t = 0; t < 4; ++t) {
        bh4[t] = bh[lr + 16 * t];
        b14[t] = b1[lr + 16 * t];
        b24[t] = b2[lr + 16 * t];
    }
    const float escale = 1.0f + eps[0];

    for (int strip = gw; strip < nstrips; strip += nw) {
        const int rbase = strip * 16;

        float vh[4][4];
#pragma unroll
        for (int t = 0; t < 4; ++t)
#pragma unroll
            for (int rg = 0; rg < 4; ++rg)
                vh[t][rg] = hres[(size_t)min(rbase + lrow4 + rg, N - 1) * DIM + lr + 16 * t];

        // ---- stage 1: aggr @ Wh^T ----
        const int arow = min(rbase + lr, N - 1);
        short8 ah[2], al[2];
#pragma unroll
        for (int s = 0; s < 2; ++s) {
            const float4 p0 = *reinterpret_cast<const float4*>(aggr + (size_t)arow * DIM + 32 * s + lk);
            const float4 p1 = *reinterpret_cast<const float4*>(aggr + (size_t)arow * DIM + 32 * s + lk + 4);
            float f[8] = {p0.x, p0.y, p0.z, p0.w, p1.x, p1.y, p1.z, p1.w};
            cvt8(f, ah[s], al[s]);
        }
        short8 lo_[4][2];
#pragma unroll
        for (int t = 0; t < 4; ++t)
#pragma unroll
            for (int s = 0; s < 2; ++s)
                lo_[t][s] = wf[(((1 * 4 + t) * 2 + s) * 2 + 1) * 64 + l];
        f32x4 acc[4];
#pragma unroll
        for (int t = 0; t < 4; ++t) acc[t] = (f32x4){bh4[t], bh4[t], bh4[t], bh4[t]};
#pragma unroll
        for (int s = 0; s < 2; ++s) {
#pragma unroll
            for (int t = 0; t < 4; ++t) acc[t] = MFMA16(ah[s], whh[t][s], acc[t]);
#pragma unroll
            for (int t = 0; t < 4; ++t) acc[t] = MFMA16(ah[s], lo_[t][s], acc[t]);
#pragma unroll
            for (int t = 0; t < 4; ++t) acc[t] = MFMA16(al[s], whh[t][s], acc[t]);
        }
#pragma unroll
        for (int t = 0; t < 4; ++t)
#pragma unroll
            for (int rg = 0; rg < 4; ++rg)
                zw[(lrow4 + rg) * 68 + lr + 16 * t] = fmaf(escale, vh[t][rg], acc[t][rg]);
        asm volatile("s_waitcnt lgkmcnt(0)" ::: "memory");

        // ---- stage 2: z @ W1^T, relu ----
        short8 zh[2], zl[2];
#pragma unroll
        for (int s = 0; s < 2; ++s) {
            const float4 q0 = *reinterpret_cast<const float4*>(zw + lr * 68 + 32 * s + lk);
            const float4 q1 = *reinterpret_cast<const float4*>(zw + lr * 68 + 32 * s + lk + 4);
            float f[8] = {q0.x, q0.y, q0.z, q0.w, q1.x, q1.y, q1.z, q1.w};
            cvt8(f, zh[s], zl[s]);
        }
#pragma unroll
        for (int t = 0; t < 4; ++t)
#pragma unroll
            for (int s = 0; s < 2; ++s)
                lo_[t][s] = wf[(((2 * 4 + t) * 2 + s) * 2 + 1) * 64 + l];
#pragma unroll
        for (int t = 0; t < 4; ++t) acc[t] = (f32x4){b14[t], b14[t], b14[t], b14[t]};
#pragma unroll
        for (int s = 0; s < 2; ++s) {
#pragma unroll
            for (int t = 0; t < 4; ++t) acc[t] = MFMA16(zh[s], w1h[t][s], acc[t]);
#pragma unroll
            for (int t = 0; t < 4; ++t) acc[t] = MFMA16(zh[s], lo_[t][s], acc[t]);
#pragma unroll
            for (int t = 0; t < 4; ++t) acc[t] = MFMA16(zl[s], w1h[t][s], acc[t]);
        }
#pragma unroll
        for (int t = 0; t < 4; ++t)
#pragma unroll
            for (int rg = 0; rg < 4; ++rg)
                zw[(lrow4 + rg) * 68 + lr + 16 * t] = fmaxf(acc[t][rg], 0.f);
        asm volatile("s_waitcnt lgkmcnt(0)" ::: "memory");

        // ---- stage 3: hid @ W2^T ----
        short8 hh[2], hl[2];
#pragma unroll
        for (int s = 0; s < 2; ++s) {
            const float4 q0 = *reinterpret_cast<const float4*>(zw + lr * 68 + 32 * s + lk);
            const float4 q1 = *reinterpret_cast<const float4*>(zw + lr * 68 + 32 * s + lk + 4);
            float f[8] = {q0.x, q0.y, q0.z, q0.w, q1.x, q1.y, q1.z, q1.w};
            cvt8(f, hh[s], hl[s]);
        }
#pragma unroll
        for (int t = 0; t < 4; ++t)
#pragma unroll
            for (int s = 0; s < 2; ++s)
                lo_[t][s] = wf[(((3 * 4 + t) * 2 + s) * 2 + 1) * 64 + l];
#pragma unroll
        for (int t = 0; t < 4; ++t) acc[t] = (f32x4){b24[t], b24[t], b24[t], b24[t]};
#pragma unroll
        for (int s = 0; s < 2; ++s) {
#pragma unroll
            for (int t = 0; t < 4; ++t) acc[t] = MFMA16(hh[s], w2h[t][s], acc[t]);
#pragma unroll
            for (int t = 0; t < 4; ++t) acc[t] = MFMA16(hh[s], lo_[t][s], acc[t]);
#pragma unroll
            for (int t = 0; t < 4; ++t) acc[t] = MFMA16(hl[s], w2h[t][s], acc[t]);
        }
#pragma unroll
        for (int t = 0; t < 4; ++t)
#pragma unroll
            for (int rg = 0; rg < 4; ++rg) {
                const int row = rbase + lrow4 + rg;
                if (row < N) out[(size_t)row * DIM + lr + 16 * t] = acc[t][rg];
            }
    }
}

extern "C" void kernel_launch(void* const* d_in, const int* in_sizes, int n_in,
                              void* d_out, int out_size, void* d_ws, size_t ws_size,
                              hipStream_t stream) {
    const float* x        = (const float*)d_in[0];
    const int*   ei       = (const int*)d_in[1];
    const int*   esign    = (const int*)d_in[2];
    const float* Wl_w     = (const float*)d_in[3];
    const float* Wl_b     = (const float*)d_in[4];
    const float* sign_tab = (const float*)d_in[5];
    const float* Wh_w     = (const float*)d_in[6];
    const float* Wh_b     = (const float*)d_in[7];
    const float* w1       = (const float*)d_in[8];
    const float* b1       = (const float*)d_in[9];
    const float* w2       = (const float*)d_in[10];
    const float* b2       = (const float*)d_in[11];
    const float* eps      = (const float*)d_in[12];
    float* out = (float*)d_out;

    const int N = in_sizes[0] / DIM;
    const int E = in_sizes[2];

    float* h       = (float*)d_ws;
    float* aggr    = h + (size_t)N * DIM;
    int*   records = (int*)aggr;                 // alias: dead before attn writes aggr
    int*   edata   = (int*)(aggr + (size_t)N * DIM);
    int*   bcursor = edata + (E + 520);          // 512 sentinel slots + slack
    int*   offsets = bcursor + NBUCK;            // N+1 ints
    short8* wf     = (short8*)(offsets + ((N + 1 + 3) & ~3));  // 16KB, 16B-aligned
    unsigned short* hb = (unsigned short*)d_out; // bf16 mirror: d_out is dead
                                                 // scratch until tail overwrites it

    const int NB = (E + CHUNK - 1) / CHUNK;

    // frag prep + bcursor zero + edata sentinels + offsets[N]
    prep_kernel<<<1, 256, 0, stream>>>(Wl_w, Wh_w, w1, w2, wf, bcursor,
                                       edata, offsets, N, E);

    // fused: h-projection GEMM (odd blocks) || edge binning (even blocks)
    gemmbin_kernel<<<2 * NB, 256, 0, stream>>>(x, wf, Wl_b, h, hb, N,
                                               ei, esign, bcursor, records, E, NB);

    // per-bucket CSR finalize (in-block scan of bucket counts)
    build_kernel<<<NBUCK, 256, 0, stream>>>(records, bcursor, offsets, edata, N);

    // segment softmax + aggregation (bf16 gathers)
    attn_kernel<<<(N + 15) / 16, 256, 0, stream>>>(h, hb, offsets, edata, sign_tab, aggr, N);

    // fused tail (MFMA): z -> relu mlp -> out
    tail_kernel<<<512, 256, 0, stream>>>(aggr, h, wf, Wh_b, b1, b2, eps, out, N);
}